// Round 4
// baseline (1465.032 us; speedup 1.0000x reference)
//
#include <hip/hip_runtime.h>
#include <stdint.h>

#define T_TOK 4096
#define H_DIM 2048
#define I_DIM 4096
#define N_EXP 8

typedef __attribute__((ext_vector_type(8))) short bf16x8;     // MFMA A/B frag (8 bf16)
typedef __attribute__((ext_vector_type(4))) float f32x4;      // MFMA C/D frag
typedef __attribute__((ext_vector_type(8))) unsigned short u16x8;

__device__ __forceinline__ unsigned short f2bf(float x) {
    union { float f; unsigned u; } v; v.f = x;
    unsigned r = v.u + 0x7FFF + ((v.u >> 16) & 1);   // RNE
    return (unsigned short)(r >> 16);
}

__device__ __forceinline__ u16x8 cvt8(float4 a, float4 b) {
    u16x8 o;
    o[0] = f2bf(a.x); o[1] = f2bf(a.y); o[2] = f2bf(a.z); o[3] = f2bf(a.w);
    o[4] = f2bf(b.x); o[5] = f2bf(b.y); o[6] = f2bf(b.z); o[7] = f2bf(b.w);
    return o;
}

// Direct global->LDS async copy, 16B per lane. LDS dest = wave-uniform base + lane*16.
__device__ __forceinline__ void async_cp16(const void* g, const unsigned short* lds_base) {
    __builtin_amdgcn_global_load_lds(
        (const __attribute__((address_space(1))) unsigned*)g,
        (__attribute__((address_space(3))) unsigned*)(unsigned)(uintptr_t)lds_base,
        16, 0, 0);
}

// ---------------- routing: top-2 + softmax + bucketize (single block) ----------
__global__ void routing_kernel(const float* __restrict__ logits,
                               int* __restrict__ counts, int* __restrict__ offsets,
                               int* __restrict__ btok, float* __restrict__ bw,
                               int* __restrict__ tok2slot) {
    __shared__ int s_cnt[N_EXP];
    __shared__ int s_off[N_EXP];
    __shared__ int s_cur[N_EXP];
    const int tid = threadIdx.x;   // 256 threads, 16 tokens each
    if (tid < N_EXP) s_cnt[tid] = 0;
    __syncthreads();

    int e0a[16], e1a[16]; float w0a[16], w1a[16];
    #pragma unroll
    for (int it = 0; it < 16; ++it) {
        int t = tid + it * 256;
        float l[8];
        #pragma unroll
        for (int e = 0; e < 8; ++e) l[e] = logits[t * 8 + e];
        int b0 = 0; float v0 = l[0];
        #pragma unroll
        for (int e = 1; e < 8; ++e) if (l[e] > v0) { v0 = l[e]; b0 = e; }
        int b1 = (b0 == 0) ? 1 : 0; float v1 = l[b1];
        #pragma unroll
        for (int e = 0; e < 8; ++e) if (e != b0 && l[e] > v1) { v1 = l[e]; b1 = e; }
        float w0 = 1.0f / (1.0f + __expf(v1 - v0));
        e0a[it] = b0; e1a[it] = b1; w0a[it] = w0; w1a[it] = 1.0f - w0;
        atomicAdd(&s_cnt[b0], 1);
        atomicAdd(&s_cnt[b1], 1);
    }
    __syncthreads();
    if (tid == 0) {
        int acc = 0;
        for (int e = 0; e < N_EXP; ++e) { s_off[e] = acc; s_cur[e] = acc; acc += s_cnt[e]; }
    }
    __syncthreads();
    if (tid < N_EXP) { counts[tid] = s_cnt[tid]; offsets[tid] = s_off[tid]; }
    #pragma unroll
    for (int it = 0; it < 16; ++it) {
        int t = tid + it * 256;
        int p0 = atomicAdd(&s_cur[e0a[it]], 1);
        btok[p0] = t; bw[p0] = w0a[it];
        int p1 = atomicAdd(&s_cur[e1a[it]], 1);
        btok[p1] = t; bw[p1] = w1a[it];
        tok2slot[2 * t] = p0;
        tok2slot[2 * t + 1] = p1;
    }
}

// ---------------- fp32 -> bf16 convert (8 floats / thread) -------------------
__global__ void cvt_kernel(const float* __restrict__ x, unsigned short* __restrict__ xb) {
    int i = blockIdx.x * blockDim.x + threadIdx.x;   // over groups of 8 floats
    float4 a = ((const float4*)x)[2 * i];
    float4 b = ((const float4*)x)[2 * i + 1];
    ((u16x8*)xb)[i] = cvt8(a, b);
}

// =====================  PATH A: fused-convert pipelined GEMMs ================
//
// Weights stay fp32 in HBM; conversion is fused into GEMM staging:
//   A (bf16 activations): global_load_lds, pre-swizzled source chunk.
//   B (fp32 weights): global_load -> VGPR (issued BEFORE the MFMA cluster,
//     lands under its shadow) -> f2bf -> ds_write_b128 to the swizzled slot
//     (write slot = chunk ^ ((row>>1)&3), matching the read swizzle
//     xq = q ^ ((c>>1)&3); layout identical to the verified gload_lds path).
// Ring-4 of K=32 halves, lookahead 2:
//   phase h: {ds_read frags(slot h&3) | B-reg loads (h+2) | A gload_lds (h+2)
//             | sched_barrier | setprio(1) MFMA setprio(0)
//             | cvt+ds_write B (h+2) | lgkmcnt(0) | vmcnt(2) | barrier}
// Invariants:
//   - vmcnt(2) at end of phase h: only phase-h's 2 A-gloads may remain =>
//     all A-gloads for half h+1 (issued phase h-1) have landed.
//   - lgkmcnt(0) drains frag reads (slot h&3) and B ds_writes ((h+2)&3);
//     slot (h+2)&3 == (h-2)&3 was last read in phase h-2 (drained then).
//   - B regs are consumed by cvt in the same phase (compiler auto-waits).

// GEMM1: h[slot,i] = silu(x@W1^T) * (x@W3^T).  BM=256 x BN=128, K=H_DIM.
__global__ __launch_bounds__(512, 2)
void gemm1p_kernel(const unsigned short* __restrict__ Xb,
                   const float* __restrict__ W1,
                   const float* __restrict__ W3,
                   const int* __restrict__ counts,
                   const int* __restrict__ offsets,
                   const int* __restrict__ btok,
                   unsigned short* __restrict__ hbuf) {
    const int e = blockIdx.z;
    const int ne = counts[e];
    const int mt = blockIdx.y;
    if (mt * 256 >= ne) return;
    const int nt = blockIdx.x;
    const int off = offsets[e];

    __shared__ unsigned short sA[4][256 * 32];    // 64 KB  (ring of K-halves)
    __shared__ unsigned short sB1[4][128 * 32];   // 32 KB
    __shared__ unsigned short sB3[4][128 * 32];   // 32 KB  -> exactly 128 KB

    const int tid = threadIdx.x;
    const int lane = tid & 63;
    const int wv = tid >> 6;
    const int wm = (wv >> 1) << 6;   // 4 M-waves of 64
    const int wn = (wv & 1) << 6;    // 2 N-waves of 64
    const int q = lane >> 4;
    const int c = lane & 15;
    const int xq = q ^ ((c >> 1) & 3);          // swizzled read slot

    const int aoff = (wm + c) * 32 + xq * 8;
    const int boff = (wn + c) * 32 + xq * 8;

    // staging: wave wv covers rows wv*16..wv*16+15 of each 128-row group
    const int srow = wv * 16 + (lane >> 2);           // 0..127
    const int sg = (lane & 3) ^ ((lane >> 3) & 3);    // swizzle chunk for row srow

    int sl0 = mt * 256 + srow;        if (sl0 >= ne) sl0 = ne - 1;
    int sl1 = mt * 256 + srow + 128;  if (sl1 >= ne) sl1 = ne - 1;
    const int tok0 = btok[off + sl0];
    const int tok1 = btok[off + sl1];

    // A: bf16, pre-swizzled source chunk + linear LDS dest (gload_lds rule)
    const unsigned short* gA0 = Xb + (size_t)tok0 * H_DIM + sg * 8;
    const unsigned short* gA1 = Xb + (size_t)tok1 * H_DIM + sg * 8;
    // B: fp32, natural chunk; swizzle applied on the ds_write address
    const size_t wrow = (size_t)e * I_DIM + nt * 128 + srow;
    const float* gW1 = W1 + wrow * H_DIM + (lane & 3) * 8;
    const float* gW3 = W3 + wrow * H_DIM + (lane & 3) * 8;
    const int bwro = srow * 32 + sg * 8;    // ds_write element offset (16B store)

    const int dofsA0 = wv * 512;            // LDS element offsets (wave-uniform)
    const int dofsA1 = 4096 + wv * 512;

    f32x4 accg[4][4], accu[4][4];
    const f32x4 zero = {0.0f, 0.0f, 0.0f, 0.0f};
    #pragma unroll
    for (int i = 0; i < 4; ++i)
        #pragma unroll
        for (int j = 0; j < 4; ++j) { accg[i][j] = zero; accu[i][j] = zero; }

    // ---- prologue: halves 0,1 ----
    {
        float4 a0 = *(const float4*)(gW1);
        float4 a1 = *(const float4*)(gW1 + 4);
        float4 b0 = *(const float4*)(gW3);
        float4 b1 = *(const float4*)(gW3 + 4);
        float4 c0 = *(const float4*)(gW1 + 32);
        float4 c1 = *(const float4*)(gW1 + 36);
        float4 d0 = *(const float4*)(gW3 + 32);
        float4 d1 = *(const float4*)(gW3 + 36);
        *(u16x8*)(&sB1[0][bwro]) = cvt8(a0, a1);
        *(u16x8*)(&sB3[0][bwro]) = cvt8(b0, b1);
        *(u16x8*)(&sB1[1][bwro]) = cvt8(c0, c1);
        *(u16x8*)(&sB3[1][bwro]) = cvt8(d0, d1);
    }
    async_cp16(gA0,      &sA[0][dofsA0]);
    async_cp16(gA1,      &sA[0][dofsA1]);
    async_cp16(gA0 + 32, &sA[1][dofsA0]);
    async_cp16(gA1 + 32, &sA[1][dofsA1]);
    asm volatile("s_waitcnt lgkmcnt(0)" ::: "memory");
    asm volatile("s_waitcnt vmcnt(2)" ::: "memory");   // half 0's A landed
    __builtin_amdgcn_s_barrier();
    __builtin_amdgcn_sched_barrier(0);

    const int NT = H_DIM / 32;   // 64
    #pragma unroll 4
    for (int h = 0; h < NT; ++h) {
        const int cs = h & 3;
        bf16x8 af[4], b1f[4], b3f[4];
        #pragma unroll
        for (int i = 0; i < 4; ++i) af[i]  = *(const bf16x8*)(&sA[cs][aoff + i * 512]);
        #pragma unroll
        for (int j = 0; j < 4; ++j) b1f[j] = *(const bf16x8*)(&sB1[cs][boff + j * 512]);
        #pragma unroll
        for (int j = 0; j < 4; ++j) b3f[j] = *(const bf16x8*)(&sB3[cs][boff + j * 512]);

        const bool stg = (h + 2) < NT;
        float4 r10, r11, r30, r31;
        if (stg) {
            const float* p1 = gW1 + (size_t)(h + 2) * 32;
            const float* p3 = gW3 + (size_t)(h + 2) * 32;
            r10 = *(const float4*)(p1);
            r11 = *(const float4*)(p1 + 4);
            r30 = *(const float4*)(p3);
            r31 = *(const float4*)(p3 + 4);
            const int ns = (h + 2) & 3;
            async_cp16(gA0 + (h + 2) * 32, &sA[ns][dofsA0]);
            async_cp16(gA1 + (h + 2) * 32, &sA[ns][dofsA1]);
        }
        __builtin_amdgcn_sched_barrier(0);
        __builtin_amdgcn_s_setprio(1);
        #pragma unroll
        for (int i = 0; i < 4; ++i)
            #pragma unroll
            for (int j = 0; j < 4; ++j)
                accg[i][j] = __builtin_amdgcn_mfma_f32_16x16x32_bf16(af[i], b1f[j], accg[i][j], 0, 0, 0);
        #pragma unroll
        for (int i = 0; i < 4; ++i)
            #pragma unroll
            for (int j = 0; j < 4; ++j)
                accu[i][j] = __builtin_amdgcn_mfma_f32_16x16x32_bf16(af[i], b3f[j], accu[i][j], 0, 0, 0);
        __builtin_amdgcn_s_setprio(0);

        if (stg) {
            const int ns = (h + 2) & 3;
            *(u16x8*)(&sB1[ns][bwro]) = cvt8(r10, r11);
            *(u16x8*)(&sB3[ns][bwro]) = cvt8(r30, r31);
        }
        if (h + 1 < NT) {
            asm volatile("s_waitcnt lgkmcnt(0)" ::: "memory");
            if (stg) asm volatile("s_waitcnt vmcnt(2)" ::: "memory");
            else     asm volatile("s_waitcnt vmcnt(0)" ::: "memory");
            __builtin_amdgcn_s_barrier();
            __builtin_amdgcn_sched_barrier(0);
        }
    }

    // epilogue: silu(gate)*up -> bf16
    #pragma unroll
    for (int i = 0; i < 4; ++i) {
        #pragma unroll
        for (int r = 0; r < 4; ++r) {
            int mloc = wm + i * 16 + q * 4 + r;
            int slot = mt * 256 + mloc;
            if (slot < ne) {
                size_t rowbase = (size_t)(off + slot) * I_DIM + nt * 128 + wn;
                #pragma unroll
                for (int j = 0; j < 4; ++j) {
                    float g = accg[i][j][r];
                    float u = accu[i][j][r];
                    float val = (g / (1.0f + __expf(-g))) * u;
                    hbuf[rowbase + j * 16 + c] = f2bf(val);
                }
            }
        }
    }
}

// GEMM2: y[slot,h] = h[slot] @ W2^T.  BM=256 x BN=256, K=I_DIM. Ring-4, 128 KB.
__global__ __launch_bounds__(512, 2)
void gemm2p_kernel(const unsigned short* __restrict__ hbuf,
                   const float* __restrict__ W2,
                   const int* __restrict__ counts,
                   const int* __restrict__ offsets,
                   float* __restrict__ ybuf) {
    const int e = blockIdx.z;
    const int ne = counts[e];
    const int mt = blockIdx.y;
    if (mt * 256 >= ne) return;
    const int nt = blockIdx.x;
    const int off = offsets[e];

    __shared__ unsigned short sA[4][256 * 32];   // 64 KB
    __shared__ unsigned short sB[4][256 * 32];   // 64 KB

    const int tid = threadIdx.x;
    const int lane = tid & 63;
    const int wv = tid >> 6;
    const int wm = (wv >> 2) << 7;   // 2 M-waves of 128
    const int wn = (wv & 3) << 6;    // 4 N-waves of 64
    const int q = lane >> 4;
    const int c = lane & 15;
    const int xq = q ^ ((c >> 1) & 3);

    const int aoff = (wm + c) * 32 + xq * 8;
    const int boff = (wn + c) * 32 + xq * 8;

    const int srow = wv * 16 + (lane >> 2);           // 0..127
    const int sg = (lane & 3) ^ ((lane >> 3) & 3);

    int slot0 = mt * 256 + srow;        if (slot0 >= ne) slot0 = ne - 1;
    int slot1 = mt * 256 + srow + 128;  if (slot1 >= ne) slot1 = ne - 1;
    const unsigned short* gA0 = hbuf + (size_t)(off + slot0) * I_DIM + sg * 8;
    const unsigned short* gA1 = hbuf + (size_t)(off + slot1) * I_DIM + sg * 8;
    // B: fp32 weights, rows nt*256+srow and +128
    const size_t wrow = (size_t)e * H_DIM + nt * 256 + srow;
    const float* gB0 = W2 + wrow * I_DIM + (lane & 3) * 8;
    const float* gB1 = gB0 + (size_t)128 * I_DIM;
    const int bwro = srow * 32 + sg * 8;              // rows 0..127; +4096 for +128

    const int dofsA0 = wv * 512;
    const int dofsA1 = 4096 + wv * 512;

    f32x4 acc[8][4];
    const f32x4 zero = {0.0f, 0.0f, 0.0f, 0.0f};
    #pragma unroll
    for (int i = 0; i < 8; ++i)
        #pragma unroll
        for (int j = 0; j < 4; ++j) acc[i][j] = zero;

    // ---- prologue: halves 0,1 ----
    {
        float4 a0 = *(const float4*)(gB0);
        float4 a1 = *(const float4*)(gB0 + 4);
        float4 b0 = *(const float4*)(gB1);
        float4 b1 = *(const float4*)(gB1 + 4);
        float4 c0 = *(const float4*)(gB0 + 32);
        float4 c1 = *(const float4*)(gB0 + 36);
        float4 d0 = *(const float4*)(gB1 + 32);
        float4 d1 = *(const float4*)(gB1 + 36);
        *(u16x8*)(&sB[0][bwro])        = cvt8(a0, a1);
        *(u16x8*)(&sB[0][bwro + 4096]) = cvt8(b0, b1);
        *(u16x8*)(&sB[1][bwro])        = cvt8(c0, c1);
        *(u16x8*)(&sB[1][bwro + 4096]) = cvt8(d0, d1);
    }
    async_cp16(gA0,      &sA[0][dofsA0]);
    async_cp16(gA1,      &sA[0][dofsA1]);
    async_cp16(gA0 + 32, &sA[1][dofsA0]);
    async_cp16(gA1 + 32, &sA[1][dofsA1]);
    asm volatile("s_waitcnt lgkmcnt(0)" ::: "memory");
    asm volatile("s_waitcnt vmcnt(2)" ::: "memory");
    __builtin_amdgcn_s_barrier();
    __builtin_amdgcn_sched_barrier(0);

    const int NT = I_DIM / 32;   // 128
    #pragma unroll 4
    for (int h = 0; h < NT; ++h) {
        const int cs = h & 3;
        bf16x8 af[8], bfr[4];
        #pragma unroll
        for (int i = 0; i < 8; ++i) af[i]  = *(const bf16x8*)(&sA[cs][aoff + i * 512]);
        #pragma unroll
        for (int j = 0; j < 4; ++j) bfr[j] = *(const bf16x8*)(&sB[cs][boff + j * 512]);

        const bool stg = (h + 2) < NT;
        float4 r00, r01, r10, r11;
        if (stg) {
            const float* p0 = gB0 + (size_t)(h + 2) * 32;
            const float* p1 = gB1 + (size_t)(h + 2) * 32;
            r00 = *(const float4*)(p0);
            r01 = *(const float4*)(p0 + 4);
            r10 = *(const float4*)(p1);
            r11 = *(const float4*)(p1 + 4);
            const int ns = (h + 2) & 3;
            async_cp16(gA0 + (h + 2) * 32, &sA[ns][dofsA0]);
            async_cp16(gA1 + (h + 2) * 32, &sA[ns][dofsA1]);
        }
        __builtin_amdgcn_sched_barrier(0);
        __builtin_amdgcn_s_setprio(1);
        #pragma unroll
        for (int i = 0; i < 8; ++i)
            #pragma unroll
            for (int j = 0; j < 4; ++j)
                acc[i][j] = __builtin_amdgcn_mfma_f32_16x16x32_bf16(af[i], bfr[j], acc[i][j], 0, 0, 0);
        __builtin_amdgcn_s_setprio(0);

        if (stg) {
            const int ns = (h + 2) & 3;
            *(u16x8*)(&sB[ns][bwro])        = cvt8(r00, r01);
            *(u16x8*)(&sB[ns][bwro + 4096]) = cvt8(r10, r11);
        }
        if (h + 1 < NT) {
            asm volatile("s_waitcnt lgkmcnt(0)" ::: "memory");
            if (stg) asm volatile("s_waitcnt vmcnt(2)" ::: "memory");
            else     asm volatile("s_waitcnt vmcnt(0)" ::: "memory");
            __builtin_amdgcn_s_barrier();
            __builtin_amdgcn_sched_barrier(0);
        }
    }

    #pragma unroll
    for (int i = 0; i < 8; ++i) {
        #pragma unroll
        for (int r = 0; r < 4; ++r) {
            int mloc = wm + i * 16 + q * 4 + r;
            int slot = mt * 256 + mloc;
            if (slot < ne) {
                float* obase = ybuf + (size_t)(off + slot) * H_DIM + nt * 256 + wn;
                #pragma unroll
                for (int j = 0; j < 4; ++j)
                    obase[j * 16 + c] = acc[i][j][r];
            }
        }
    }
}

// combine: out[t] = w0 * y[slot0] + w1 * y[slot1]
__global__ void combine_kernel(const float* __restrict__ ybuf,
                               const float* __restrict__ bw,
                               const int* __restrict__ tok2slot,
                               float* __restrict__ out) {
    int i = blockIdx.x * blockDim.x + threadIdx.x;   // over float4 of out
    int t = i >> 9;            // H/4 = 512
    int h4 = i & 511;
    int p0 = tok2slot[2 * t], p1 = tok2slot[2 * t + 1];
    float w0 = bw[p0], w1 = bw[p1];
    float4 a = ((const float4*)(ybuf + (size_t)p0 * H_DIM))[h4];
    float4 b = ((const float4*)(ybuf + (size_t)p1 * H_DIM))[h4];
    float4 o;
    o.x = w0 * a.x + w1 * b.x;
    o.y = w0 * a.y + w1 * b.y;
    o.z = w0 * a.z + w1 * b.z;
    o.w = w0 * a.w + w1 * b.w;
    ((float4*)(out + (size_t)t * H_DIM))[h4] = o;
}

// =====================  PATH B: fallback (fp32 weights in-loop) ==============

__global__ __launch_bounds__(256, 2)
void gemm1_kernel(const unsigned short* __restrict__ Xb,
                  const float* __restrict__ W1,
                  const float* __restrict__ W3,
                  const int* __restrict__ counts,
                  const int* __restrict__ offsets,
                  const int* __restrict__ btok,
                  unsigned short* __restrict__ hbuf) {
    const int e = blockIdx.z;
    const int ne = counts[e];
    const int mt = blockIdx.y;
    if (mt * 128 >= ne) return;
    const int nt = blockIdx.x;
    const int off = offsets[e];

    __shared__ unsigned short sA[128][32];
    __shared__ unsigned short sB1[128][32];
    __shared__ unsigned short sB3[128][32];
    __shared__ int s_tok[128];

    const int tid = threadIdx.x;
    if (tid < 128) {
        int slot = mt * 128 + tid;
        s_tok[tid] = (slot < ne) ? btok[off + slot] : -1;
    }

    const float* __restrict__ pB1 = W1 + (size_t)e * I_DIM * H_DIM + (size_t)(nt * 128) * H_DIM;
    const float* __restrict__ pB3 = W3 + (size_t)e * I_DIM * H_DIM + (size_t)(nt * 128) * H_DIM;

    const int lane = tid & 63;
    const int wv = tid >> 6;
    const int wm = (wv >> 1) << 6;
    const int wn = (wv & 1) << 6;
    const int q = lane >> 4;
    const int c = lane & 15;

    f32x4 accg[4][4], accu[4][4];
    const f32x4 zero = {0.0f, 0.0f, 0.0f, 0.0f};
    #pragma unroll
    for (int i = 0; i < 4; ++i)
        #pragma unroll
        for (int j = 0; j < 4; ++j) { accg[i][j] = zero; accu[i][j] = zero; }

    const int srow = tid >> 2;
    const int schunk = (tid & 3) * 8;

    for (int kt = 0; kt < H_DIM; kt += 32) {
        __syncthreads();
        #pragma unroll
        for (int p = 0; p < 2; ++p) {
            int r = srow + p * 64;
            int tok = s_tok[r];
            u16x8 av = {0, 0, 0, 0, 0, 0, 0, 0};
            if (tok >= 0)
                av = *(const u16x8*)(Xb + (size_t)tok * H_DIM + kt + schunk);
            *(u16x8*)(&sA[r][schunk]) = av;

            const float* b1 = pB1 + (size_t)r * H_DIM + kt + schunk;
            *(u16x8*)(&sB1[r][schunk]) = cvt8(*(const float4*)(b1), *(const float4*)(b1 + 4));

            const float* b3 = pB3 + (size_t)r * H_DIM + kt + schunk;
            *(u16x8*)(&sB3[r][schunk]) = cvt8(*(const float4*)(b3), *(const float4*)(b3 + 4));
        }
        __syncthreads();

        bf16x8 af[4], b1f[4], b3f[4];
        #pragma unroll
        for (int i = 0; i < 4; ++i)
            af[i] = *(const bf16x8*)(&sA[wm + i * 16 + c][q * 8]);
        #pragma unroll
        for (int j = 0; j < 4; ++j) {
            b1f[j] = *(const bf16x8*)(&sB1[wn + j * 16 + c][q * 8]);
            b3f[j] = *(const bf16x8*)(&sB3[wn + j * 16 + c][q * 8]);
        }
        #pragma unroll
        for (int i = 0; i < 4; ++i)
            #pragma unroll
            for (int j = 0; j < 4; ++j) {
                accg[i][j] = __builtin_amdgcn_mfma_f32_16x16x32_bf16(af[i], b1f[j], accg[i][j], 0, 0, 0);
                accu[i][j] = __builtin_amdgcn_mfma_f32_16x16x32_bf16(af[i], b3f[j], accu[i][j], 0, 0, 0);
            }
    }

    #pragma unroll
    for (int i = 0; i < 4; ++i) {
        #pragma unroll
        for (int r = 0; r < 4; ++r) {
            int mloc = wm + i * 16 + q * 4 + r;
            int slot = mt * 128 + mloc;
            if (slot < ne) {
                size_t rowbase = (size_t)(off + slot) * I_DIM + nt * 128 + wn;
                #pragma unroll
                for (int j = 0; j < 4; ++j) {
                    float g = accg[i][j][r];
                    float u = accu[i][j][r];
                    float val = (g / (1.0f + __expf(-g))) * u;
                    hbuf[rowbase + j * 16 + c] = f2bf(val);
                }
            }
        }
    }
}

__global__ __launch_bounds__(256, 2)
void gemm2_kernel(const unsigned short* __restrict__ hbuf,
                  const float* __restrict__ W2,
                  const int* __restrict__ counts,
                  const int* __restrict__ offsets,
                  const int* __restrict__ btok,
                  const float* __restrict__ bw,
                  float* __restrict__ out) {
    const int e = blockIdx.z;
    const int ne = counts[e];
    const int mt = blockIdx.y;
    if (mt * 128 >= ne) return;
    const int nt = blockIdx.x;
    const int off = offsets[e];

    __shared__ unsigned short sA[128][32];
    __shared__ unsigned short sB[128][32];

    const int tid = threadIdx.x;
    const int lane = tid & 63;
    const int wv = tid >> 6;
    const int wm = (wv >> 1) << 6;
    const int wn = (wv & 1) << 6;
    const int q = lane >> 4;
    const int c = lane & 15;

    const float* __restrict__ pB = W2 + (size_t)e * H_DIM * I_DIM + (size_t)(nt * 128) * I_DIM;

    f32x4 acc[4][4];
    const f32x4 zero = {0.0f, 0.0f, 0.0f, 0.0f};
    #pragma unroll
    for (int i = 0; i < 4; ++i)
        #pragma unroll
        for (int j = 0; j < 4; ++j) acc[i][j] = zero;

    const int srow = tid >> 2;
    const int schunk = (tid & 3) * 8;

    for (int kt = 0; kt < I_DIM; kt += 32) {
        __syncthreads();
        #pragma unroll
        for (int p = 0; p < 2; ++p) {
            int r = srow + p * 64;
            int slot = mt * 128 + r;
            u16x8 av = {0, 0, 0, 0, 0, 0, 0, 0};
            if (slot < ne)
                av = *(const u16x8*)(hbuf + (size_t)(off + slot) * I_DIM + kt + schunk);
            *(u16x8*)(&sA[r][schunk]) = av;

            const float* b = pB + (size_t)r * I_DIM + kt + schunk;
            *(u16x8*)(&sB[r][schunk]) = cvt8(*(const float4*)(b), *(const float4*)(b + 4));
        }
        __syncthreads();

        bf16x8 af[4], bfr[4];
        #pragma unroll
        for (int i = 0; i < 4; ++i)
            af[i] = *(const bf16x8*)(&sA[wm + i * 16 + c][q * 8]);
        #pragma unroll
        for (int j = 0; j < 4; ++j)
            bfr[j] = *(const bf16x8*)(&sB[wn + j * 16 + c][q * 8]);
        #pragma unroll
        for (int i = 0; i < 4; ++i)
            #pragma unroll
            for (int j = 0; j < 4; ++j)
                acc[i][j] = __builtin_amdgcn_mfma_f32_16x16x32_bf16(af[i], bfr[j], acc[i][j], 0, 0, 0);
    }

    #pragma unroll
    for (int i = 0; i < 4; ++i) {
        #pragma unroll
        for (int r = 0; r < 4; ++r) {
            int mloc = wm + i * 16 + q * 4 + r;
            int slot = mt * 128 + mloc;
            if (slot < ne) {
                int tok = btok[off + slot];
                float wgt = bw[off + slot];
                float* obase = out + (size_t)tok * H_DIM + nt * 128 + wn;
                #pragma unroll
                for (int j = 0; j < 4; ++j)
                    atomicAdd(obase + j * 16 + c, wgt * acc[i][j][r]);
            }
        }
    }
}

// ============================================================================

extern "C" void kernel_launch(void* const* d_in, const int* in_sizes, int n_in,
                              void* d_out, int out_size, void* d_ws, size_t ws_size,
                              hipStream_t stream) {
    const float* hs = (const float*)d_in[0];   // [T, H]
    const float* rl = (const float*)d_in[1];   // [T, E]
    const float* w1 = (const float*)d_in[2];   // [E, I, H]
    const float* w3 = (const float*)d_in[3];   // [E, I, H]
    const float* w2 = (const float*)d_in[4];   // [E, H, I]
    float* out = (float*)d_out;

    char* ws = (char*)d_ws;
    // meta region (first 1 MB)
    int*   counts   = (int*)(ws);
    int*   offsets  = (int*)(ws + 256);
    int*   btok     = (int*)(ws + 4096);            // 8192 ints
    float* bw       = (float*)(ws + 36864);         // 8192 floats
    int*   tok2slot = (int*)(ws + 69632);           // 8192 ints

    const size_t MB = 1ull << 20;
    const size_t NEED_A = 146 * MB;

    if (ws_size >= NEED_A) {
        // -------- Path A: fused-convert pipelined GEMMs ---------------------
        unsigned short* Xb   = (unsigned short*)(ws + 1 * MB);     // 16 MB
        unsigned short* hbuf = (unsigned short*)(ws + 17 * MB);    // 64 MB
        float*          ybuf = (float*)(ws + 81 * MB);             // 64 MB

        routing_kernel<<<1, 256, 0, stream>>>(rl, counts, offsets, btok, bw, tok2slot);

        cvt_kernel<<<(T_TOK * H_DIM / 8) / 256, 256, 0, stream>>>(hs, Xb);

        gemm1p_kernel<<<dim3(I_DIM / 128, 32, N_EXP), 512, 0, stream>>>(
            Xb, w1, w3, counts, offsets, btok, hbuf);

        gemm2p_kernel<<<dim3(H_DIM / 256, 32, N_EXP), 512, 0, stream>>>(
            hbuf, w2, counts, offsets, ybuf);

        combine_kernel<<<(T_TOK * (H_DIM / 4)) / 256, 256, 0, stream>>>(
            ybuf, bw, tok2slot, out);
    } else {
        // -------- Path B: fallback (known-good round-1 structure) -----------
        unsigned short* Xb   = (unsigned short*)(ws + 1 * MB);            // 16 MB
        unsigned short* hbuf = (unsigned short*)(ws + 32 * MB);           // 64 MB

        hipMemsetAsync(out, 0, (size_t)T_TOK * H_DIM * sizeof(float), stream);

        routing_kernel<<<1, 256, 0, stream>>>(rl, counts, offsets, btok, bw, tok2slot);

        cvt_kernel<<<(T_TOK * H_DIM / 8) / 256, 256, 0, stream>>>(hs, Xb);

        gemm1_kernel<<<dim3(I_DIM / 128, T_TOK / 128, N_EXP), 256, 0, stream>>>(
            Xb, w1, w3, counts, offsets, btok, hbuf);

        gemm2_kernel<<<dim3(H_DIM / 128, T_TOK / 128, N_EXP), 256, 0, stream>>>(
            hbuf, w2, counts, offsets, btok, bw, out);
    }
}

// Round 5
// 1308.183 us; speedup vs baseline: 1.1199x; 1.1199x over previous
//
#include <hip/hip_runtime.h>
#include <stdint.h>

#define T_TOK 4096
#define H_DIM 2048
#define I_DIM 4096
#define N_EXP 8

typedef __attribute__((ext_vector_type(8))) short bf16x8;     // MFMA A/B frag (8 bf16)
typedef __attribute__((ext_vector_type(4))) float f32x4;      // MFMA C/D frag
typedef __attribute__((ext_vector_type(8))) unsigned short u16x8;

__device__ __forceinline__ unsigned short f2bf(float x) {
    union { float f; unsigned u; } v; v.f = x;
    unsigned r = v.u + 0x7FFF + ((v.u >> 16) & 1);   // RNE
    return (unsigned short)(r >> 16);
}

__device__ __forceinline__ u16x8 cvt8(float4 a, float4 b) {
    u16x8 o;
    o[0] = f2bf(a.x); o[1] = f2bf(a.y); o[2] = f2bf(a.z); o[3] = f2bf(a.w);
    o[4] = f2bf(b.x); o[5] = f2bf(b.y); o[6] = f2bf(b.z); o[7] = f2bf(b.w);
    return o;
}

// Direct global->LDS async copy, 16B per lane. LDS dest = wave-uniform base + lane*16.
__device__ __forceinline__ void async_cp16(const void* g, const unsigned short* lds_base) {
    __builtin_amdgcn_global_load_lds(
        (const __attribute__((address_space(1))) unsigned*)g,
        (__attribute__((address_space(3))) unsigned*)(unsigned)(uintptr_t)lds_base,
        16, 0, 0);
}

// ---------------- routing: top-2 + softmax + bucketize (single block) ----------
__global__ void routing_kernel(const float* __restrict__ logits,
                               int* __restrict__ counts, int* __restrict__ offsets,
                               int* __restrict__ btok, float* __restrict__ bw,
                               int* __restrict__ tok2slot) {
    __shared__ int s_cnt[N_EXP];
    __shared__ int s_off[N_EXP];
    __shared__ int s_cur[N_EXP];
    const int tid = threadIdx.x;   // 256 threads, 16 tokens each
    if (tid < N_EXP) s_cnt[tid] = 0;
    __syncthreads();

    int e0a[16], e1a[16]; float w0a[16], w1a[16];
    #pragma unroll
    for (int it = 0; it < 16; ++it) {
        int t = tid + it * 256;
        float l[8];
        #pragma unroll
        for (int e = 0; e < 8; ++e) l[e] = logits[t * 8 + e];
        int b0 = 0; float v0 = l[0];
        #pragma unroll
        for (int e = 1; e < 8; ++e) if (l[e] > v0) { v0 = l[e]; b0 = e; }
        int b1 = (b0 == 0) ? 1 : 0; float v1 = l[b1];
        #pragma unroll
        for (int e = 0; e < 8; ++e) if (e != b0 && l[e] > v1) { v1 = l[e]; b1 = e; }
        float w0 = 1.0f / (1.0f + __expf(v1 - v0));
        e0a[it] = b0; e1a[it] = b1; w0a[it] = w0; w1a[it] = 1.0f - w0;
        atomicAdd(&s_cnt[b0], 1);
        atomicAdd(&s_cnt[b1], 1);
    }
    __syncthreads();
    if (tid == 0) {
        int acc = 0;
        for (int e = 0; e < N_EXP; ++e) { s_off[e] = acc; s_cur[e] = acc; acc += s_cnt[e]; }
    }
    __syncthreads();
    if (tid < N_EXP) { counts[tid] = s_cnt[tid]; offsets[tid] = s_off[tid]; }
    #pragma unroll
    for (int it = 0; it < 16; ++it) {
        int t = tid + it * 256;
        int p0 = atomicAdd(&s_cur[e0a[it]], 1);
        btok[p0] = t; bw[p0] = w0a[it];
        int p1 = atomicAdd(&s_cur[e1a[it]], 1);
        btok[p1] = t; bw[p1] = w1a[it];
        tok2slot[2 * t] = p0;
        tok2slot[2 * t + 1] = p1;
    }
}

// ---------------- fp32 -> bf16 convert (8 floats / thread) -------------------
__global__ void cvt_kernel(const float* __restrict__ x, unsigned short* __restrict__ xb) {
    int i = blockIdx.x * blockDim.x + threadIdx.x;   // over groups of 8 floats
    float4 a = ((const float4*)x)[2 * i];
    float4 b = ((const float4*)x)[2 * i + 1];
    ((u16x8*)xb)[i] = cvt8(a, b);
}

// =====================  PATH A: fused-convert pipelined GEMMs ================
//
// Weights stay fp32 in HBM; conversion fused into GEMM staging with a FULL
// phase of load->use distance (the round-4 regression was issue+consume in
// the same phase):
//   phase h: {issue B-reg loads (half h+3) | ds_read frags (slot h&3)
//             | A gload_lds (half h+2) | sched_barrier | setprio(1) MFMA
//             | setprio(0) | cvt+ds_write B regs from phase h-1 (half h+2)
//             | lgkmcnt(0) | vmcnt(6) | barrier}
// Invariants:
//   - vmcnt(6) at end of phase h: only this phase's 4 B-loads + 2 A-gloads
//     may remain => A for half h+1 (issued h-1) and all older B landed.
//   - lgkmcnt(0) drains frag reads (slot h&3) and B ds_writes ((h+2)&3);
//     slot (h+2)&3 == (h-2)&3 was last read in phase h-2 (drained then).
//   - B regs consumed one full phase after issue (compiler auto-waits).
// Tail: vmcnt(2) when only A-gloads outstanding, vmcnt(0) last.
// Swizzle (verified, conflicts=0, correct): LDS pos p of row r holds global
// chunk p ^ ((r>>1)&3); A staged via pre-swizzled global source + linear
// dest, B via natural global chunk + swizzled ds_write; reads at
// xq = q ^ ((c>>1)&3).

// GEMM1: h[slot,i] = silu(x@W1^T) * (x@W3^T).  BM=256 x BN=128, K=H_DIM.
__global__ __launch_bounds__(512, 2)
void gemm1p_kernel(const unsigned short* __restrict__ Xb,
                   const float* __restrict__ W1,
                   const float* __restrict__ W3,
                   const int* __restrict__ counts,
                   const int* __restrict__ offsets,
                   const int* __restrict__ btok,
                   unsigned short* __restrict__ hbuf) {
    const int e = blockIdx.z;
    const int ne = counts[e];
    const int mt = blockIdx.y;
    if (mt * 256 >= ne) return;
    const int nt = blockIdx.x;
    const int off = offsets[e];

    __shared__ unsigned short sA[4][256 * 32];    // 64 KB  (ring of K-halves)
    __shared__ unsigned short sB1[4][128 * 32];   // 32 KB
    __shared__ unsigned short sB3[4][128 * 32];   // 32 KB  -> exactly 128 KB

    const int tid = threadIdx.x;
    const int lane = tid & 63;
    const int wv = tid >> 6;
    const int wm = (wv >> 1) << 6;   // 4 M-waves of 64
    const int wn = (wv & 1) << 6;    // 2 N-waves of 64
    const int q = lane >> 4;
    const int c = lane & 15;
    const int xq = q ^ ((c >> 1) & 3);          // swizzled read slot

    const int aoff = (wm + c) * 32 + xq * 8;
    const int boff = (wn + c) * 32 + xq * 8;

    // staging: wave wv covers rows wv*16..wv*16+15 of each 128-row group
    const int srow = wv * 16 + (lane >> 2);           // 0..127
    const int sg = (lane & 3) ^ ((lane >> 3) & 3);    // swizzle chunk for row srow

    int sl0 = mt * 256 + srow;        if (sl0 >= ne) sl0 = ne - 1;
    int sl1 = mt * 256 + srow + 128;  if (sl1 >= ne) sl1 = ne - 1;
    const int tok0 = btok[off + sl0];
    const int tok1 = btok[off + sl1];

    // A: bf16, pre-swizzled source chunk + linear LDS dest (gload_lds rule)
    const unsigned short* gA0 = Xb + (size_t)tok0 * H_DIM + sg * 8;
    const unsigned short* gA1 = Xb + (size_t)tok1 * H_DIM + sg * 8;
    // B: fp32, natural chunk; swizzle applied on the ds_write address
    const size_t wrow = (size_t)e * I_DIM + nt * 128 + srow;
    const float* gW1 = W1 + wrow * H_DIM + (lane & 3) * 8;
    const float* gW3 = W3 + wrow * H_DIM + (lane & 3) * 8;
    const int bwro = srow * 32 + sg * 8;    // ds_write element offset (16B store)

    const int dofsA0 = wv * 512;            // LDS element offsets (wave-uniform)
    const int dofsA1 = 4096 + wv * 512;

    f32x4 accg[4][4], accu[4][4];
    const f32x4 zero = {0.0f, 0.0f, 0.0f, 0.0f};
    #pragma unroll
    for (int i = 0; i < 4; ++i)
        #pragma unroll
        for (int j = 0; j < 4; ++j) { accg[i][j] = zero; accu[i][j] = zero; }

    // ---- prologue ----
    {
        float4 a0 = *(const float4*)(gW1);
        float4 a1 = *(const float4*)(gW1 + 4);
        float4 b0 = *(const float4*)(gW3);
        float4 b1 = *(const float4*)(gW3 + 4);
        float4 c0 = *(const float4*)(gW1 + 32);
        float4 c1 = *(const float4*)(gW1 + 36);
        float4 d0 = *(const float4*)(gW3 + 32);
        float4 d1 = *(const float4*)(gW3 + 36);
        *(u16x8*)(&sB1[0][bwro]) = cvt8(a0, a1);
        *(u16x8*)(&sB3[0][bwro]) = cvt8(b0, b1);
        *(u16x8*)(&sB1[1][bwro]) = cvt8(c0, c1);
        *(u16x8*)(&sB3[1][bwro]) = cvt8(d0, d1);
    }
    async_cp16(gA0,      &sA[0][dofsA0]);
    async_cp16(gA1,      &sA[0][dofsA1]);
    async_cp16(gA0 + 32, &sA[1][dofsA0]);
    async_cp16(gA1 + 32, &sA[1][dofsA1]);

    const int NT = H_DIM / 32;   // 64
    // prime regC with half 2's B
    float4 rc0, rc1, rc2, rc3, rn0, rn1, rn2, rn3;
    rc0 = *(const float4*)(gW1 + 64);
    rc1 = *(const float4*)(gW1 + 68);
    rc2 = *(const float4*)(gW3 + 64);
    rc3 = *(const float4*)(gW3 + 68);

    asm volatile("s_waitcnt lgkmcnt(0)" ::: "memory");
    asm volatile("s_waitcnt vmcnt(6)" ::: "memory");   // half 0's A landed
    __builtin_amdgcn_s_barrier();
    __builtin_amdgcn_sched_barrier(0);

#define G1_PHASE(H, RC0, RC1, RC2, RC3, RN0, RN1, RN2, RN3)                                          \
    {                                                                                                \
        const int cs = (H) & 3;                                                                      \
        if ((H) + 3 < NT) {                                                                          \
            const float* p1 = gW1 + (size_t)((H) + 3) * 32;                                          \
            const float* p3 = gW3 + (size_t)((H) + 3) * 32;                                          \
            RN0 = *(const float4*)(p1);                                                              \
            RN1 = *(const float4*)(p1 + 4);                                                          \
            RN2 = *(const float4*)(p3);                                                              \
            RN3 = *(const float4*)(p3 + 4);                                                          \
        }                                                                                            \
        bf16x8 af[4], b1f[4], b3f[4];                                                                \
        _Pragma("unroll")                                                                            \
        for (int i = 0; i < 4; ++i) af[i]  = *(const bf16x8*)(&sA[cs][aoff + i * 512]);              \
        _Pragma("unroll")                                                                            \
        for (int j = 0; j < 4; ++j) b1f[j] = *(const bf16x8*)(&sB1[cs][boff + j * 512]);             \
        _Pragma("unroll")                                                                            \
        for (int j = 0; j < 4; ++j) b3f[j] = *(const bf16x8*)(&sB3[cs][boff + j * 512]);             \
        if ((H) + 2 < NT) {                                                                          \
            const int ns = ((H) + 2) & 3;                                                            \
            async_cp16(gA0 + ((H) + 2) * 32, &sA[ns][dofsA0]);                                       \
            async_cp16(gA1 + ((H) + 2) * 32, &sA[ns][dofsA1]);                                       \
        }                                                                                            \
        __builtin_amdgcn_sched_barrier(0);                                                           \
        __builtin_amdgcn_s_setprio(1);                                                               \
        _Pragma("unroll")                                                                            \
        for (int i = 0; i < 4; ++i)                                                                  \
            _Pragma("unroll")                                                                        \
            for (int j = 0; j < 4; ++j)                                                              \
                accg[i][j] = __builtin_amdgcn_mfma_f32_16x16x32_bf16(af[i], b1f[j], accg[i][j], 0, 0, 0); \
        _Pragma("unroll")                                                                            \
        for (int i = 0; i < 4; ++i)                                                                  \
            _Pragma("unroll")                                                                        \
            for (int j = 0; j < 4; ++j)                                                              \
                accu[i][j] = __builtin_amdgcn_mfma_f32_16x16x32_bf16(af[i], b3f[j], accu[i][j], 0, 0, 0); \
        __builtin_amdgcn_s_setprio(0);                                                               \
        if ((H) + 2 < NT) {                                                                          \
            const int ns = ((H) + 2) & 3;                                                            \
            *(u16x8*)(&sB1[ns][bwro]) = cvt8(RC0, RC1);                                              \
            *(u16x8*)(&sB3[ns][bwro]) = cvt8(RC2, RC3);                                              \
        }                                                                                            \
        if ((H) + 1 < NT) {                                                                          \
            asm volatile("s_waitcnt lgkmcnt(0)" ::: "memory");                                       \
            if ((H) + 3 < NT)      asm volatile("s_waitcnt vmcnt(6)" ::: "memory");                  \
            else if ((H) + 2 < NT) asm volatile("s_waitcnt vmcnt(2)" ::: "memory");                  \
            else                   asm volatile("s_waitcnt vmcnt(0)" ::: "memory");                  \
            __builtin_amdgcn_s_barrier();                                                            \
            __builtin_amdgcn_sched_barrier(0);                                                       \
        }                                                                                            \
    }

    for (int h = 0; h < NT; h += 2) {
        G1_PHASE(h,     rc0, rc1, rc2, rc3, rn0, rn1, rn2, rn3);
        G1_PHASE(h + 1, rn0, rn1, rn2, rn3, rc0, rc1, rc2, rc3);
    }
#undef G1_PHASE

    // epilogue: silu(gate)*up -> bf16
    #pragma unroll
    for (int i = 0; i < 4; ++i) {
        #pragma unroll
        for (int r = 0; r < 4; ++r) {
            int mloc = wm + i * 16 + q * 4 + r;
            int slot = mt * 256 + mloc;
            if (slot < ne) {
                size_t rowbase = (size_t)(off + slot) * I_DIM + nt * 128 + wn;
                #pragma unroll
                for (int j = 0; j < 4; ++j) {
                    float g = accg[i][j][r];
                    float u = accu[i][j][r];
                    float val = (g / (1.0f + __expf(-g))) * u;
                    hbuf[rowbase + j * 16 + c] = f2bf(val);
                }
            }
        }
    }
}

// GEMM2: y[slot,h] = h[slot] @ W2^T.  BM=256 x BN=256, K=I_DIM. Ring-4, 128 KB.
__global__ __launch_bounds__(512, 2)
void gemm2p_kernel(const unsigned short* __restrict__ hbuf,
                   const float* __restrict__ W2,
                   const int* __restrict__ counts,
                   const int* __restrict__ offsets,
                   float* __restrict__ ybuf) {
    const int e = blockIdx.z;
    const int ne = counts[e];
    const int mt = blockIdx.y;
    if (mt * 256 >= ne) return;
    const int nt = blockIdx.x;
    const int off = offsets[e];

    __shared__ unsigned short sA[4][256 * 32];   // 64 KB
    __shared__ unsigned short sB[4][256 * 32];   // 64 KB

    const int tid = threadIdx.x;
    const int lane = tid & 63;
    const int wv = tid >> 6;
    const int wm = (wv >> 2) << 7;   // 2 M-waves of 128
    const int wn = (wv & 3) << 6;    // 4 N-waves of 64
    const int q = lane >> 4;
    const int c = lane & 15;
    const int xq = q ^ ((c >> 1) & 3);

    const int aoff = (wm + c) * 32 + xq * 8;
    const int boff = (wn + c) * 32 + xq * 8;

    const int srow = wv * 16 + (lane >> 2);           // 0..127
    const int sg = (lane & 3) ^ ((lane >> 3) & 3);

    int slot0 = mt * 256 + srow;        if (slot0 >= ne) slot0 = ne - 1;
    int slot1 = mt * 256 + srow + 128;  if (slot1 >= ne) slot1 = ne - 1;
    const unsigned short* gA0 = hbuf + (size_t)(off + slot0) * I_DIM + sg * 8;
    const unsigned short* gA1 = hbuf + (size_t)(off + slot1) * I_DIM + sg * 8;
    // B: fp32 weights, rows nt*256+srow and +128
    const size_t wrow = (size_t)e * H_DIM + nt * 256 + srow;
    const float* gB0 = W2 + wrow * I_DIM + (lane & 3) * 8;
    const float* gB1 = gB0 + (size_t)128 * I_DIM;
    const int bwro = srow * 32 + sg * 8;              // rows 0..127; +4096 for +128

    const int dofsA0 = wv * 512;
    const int dofsA1 = 4096 + wv * 512;

    f32x4 acc[8][4];
    const f32x4 zero = {0.0f, 0.0f, 0.0f, 0.0f};
    #pragma unroll
    for (int i = 0; i < 8; ++i)
        #pragma unroll
        for (int j = 0; j < 4; ++j) acc[i][j] = zero;

    // ---- prologue ----
    {
        float4 a0 = *(const float4*)(gB0);
        float4 a1 = *(const float4*)(gB0 + 4);
        float4 b0 = *(const float4*)(gB1);
        float4 b1 = *(const float4*)(gB1 + 4);
        float4 c0 = *(const float4*)(gB0 + 32);
        float4 c1 = *(const float4*)(gB0 + 36);
        float4 d0 = *(const float4*)(gB1 + 32);
        float4 d1 = *(const float4*)(gB1 + 36);
        *(u16x8*)(&sB[0][bwro])        = cvt8(a0, a1);
        *(u16x8*)(&sB[0][bwro + 4096]) = cvt8(b0, b1);
        *(u16x8*)(&sB[1][bwro])        = cvt8(c0, c1);
        *(u16x8*)(&sB[1][bwro + 4096]) = cvt8(d0, d1);
    }
    async_cp16(gA0,      &sA[0][dofsA0]);
    async_cp16(gA1,      &sA[0][dofsA1]);
    async_cp16(gA0 + 32, &sA[1][dofsA0]);
    async_cp16(gA1 + 32, &sA[1][dofsA1]);

    const int NT = I_DIM / 32;   // 128
    // prime regC with half 2's B
    float4 rc0, rc1, rc2, rc3, rn0, rn1, rn2, rn3;
    rc0 = *(const float4*)(gB0 + 64);
    rc1 = *(const float4*)(gB0 + 68);
    rc2 = *(const float4*)(gB1 + 64);
    rc3 = *(const float4*)(gB1 + 68);

    asm volatile("s_waitcnt lgkmcnt(0)" ::: "memory");
    asm volatile("s_waitcnt vmcnt(6)" ::: "memory");
    __builtin_amdgcn_s_barrier();
    __builtin_amdgcn_sched_barrier(0);

#define G2_PHASE(H, RC0, RC1, RC2, RC3, RN0, RN1, RN2, RN3)                                          \
    {                                                                                                \
        const int cs = (H) & 3;                                                                      \
        if ((H) + 3 < NT) {                                                                          \
            const float* p0 = gB0 + (size_t)((H) + 3) * 32;                                          \
            const float* p1 = gB1 + (size_t)((H) + 3) * 32;                                          \
            RN0 = *(const float4*)(p0);                                                              \
            RN1 = *(const float4*)(p0 + 4);                                                          \
            RN2 = *(const float4*)(p1);                                                              \
            RN3 = *(const float4*)(p1 + 4);                                                          \
        }                                                                                            \
        bf16x8 af[8], bfr[4];                                                                        \
        _Pragma("unroll")                                                                            \
        for (int i = 0; i < 8; ++i) af[i]  = *(const bf16x8*)(&sA[cs][aoff + i * 512]);              \
        _Pragma("unroll")                                                                            \
        for (int j = 0; j < 4; ++j) bfr[j] = *(const bf16x8*)(&sB[cs][boff + j * 512]);              \
        if ((H) + 2 < NT) {                                                                          \
            const int ns = ((H) + 2) & 3;                                                            \
            async_cp16(gA0 + ((H) + 2) * 32, &sA[ns][dofsA0]);                                       \
            async_cp16(gA1 + ((H) + 2) * 32, &sA[ns][dofsA1]);                                       \
        }                                                                                            \
        __builtin_amdgcn_sched_barrier(0);                                                           \
        __builtin_amdgcn_s_setprio(1);                                                               \
        _Pragma("unroll")                                                                            \
        for (int i = 0; i < 8; ++i)                                                                  \
            _Pragma("unroll")                                                                        \
            for (int j = 0; j < 4; ++j)                                                              \
                acc[i][j] = __builtin_amdgcn_mfma_f32_16x16x32_bf16(af[i], bfr[j], acc[i][j], 0, 0, 0); \
        __builtin_amdgcn_s_setprio(0);                                                               \
        if ((H) + 2 < NT) {                                                                          \
            const int ns = ((H) + 2) & 3;                                                            \
            *(u16x8*)(&sB[ns][bwro])        = cvt8(RC0, RC1);                                        \
            *(u16x8*)(&sB[ns][bwro + 4096]) = cvt8(RC2, RC3);                                        \
        }                                                                                            \
        if ((H) + 1 < NT) {                                                                          \
            asm volatile("s_waitcnt lgkmcnt(0)" ::: "memory");                                       \
            if ((H) + 3 < NT)      asm volatile("s_waitcnt vmcnt(6)" ::: "memory");                  \
            else if ((H) + 2 < NT) asm volatile("s_waitcnt vmcnt(2)" ::: "memory");                  \
            else                   asm volatile("s_waitcnt vmcnt(0)" ::: "memory");                  \
            __builtin_amdgcn_s_barrier();                                                            \
            __builtin_amdgcn_sched_barrier(0);                                                       \
        }                                                                                            \
    }

    for (int h = 0; h < NT; h += 2) {
        G2_PHASE(h,     rc0, rc1, rc2, rc3, rn0, rn1, rn2, rn3);
        G2_PHASE(h + 1, rn0, rn1, rn2, rn3, rc0, rc1, rc2, rc3);
    }
#undef G2_PHASE

    #pragma unroll
    for (int i = 0; i < 8; ++i) {
        #pragma unroll
        for (int r = 0; r < 4; ++r) {
            int mloc = wm + i * 16 + q * 4 + r;
            int slot = mt * 256 + mloc;
            if (slot < ne) {
                float* obase = ybuf + (size_t)(off + slot) * H_DIM + nt * 256 + wn;
                #pragma unroll
                for (int j = 0; j < 4; ++j)
                    obase[j * 16 + c] = acc[i][j][r];
            }
        }
    }
}

// combine: out[t] = w0 * y[slot0] + w1 * y[slot1]
__global__ void combine_kernel(const float* __restrict__ ybuf,
                               const float* __restrict__ bw,
                               const int* __restrict__ tok2slot,
                               float* __restrict__ out) {
    int i = blockIdx.x * blockDim.x + threadIdx.x;   // over float4 of out
    int t = i >> 9;            // H/4 = 512
    int h4 = i & 511;
    int p0 = tok2slot[2 * t], p1 = tok2slot[2 * t + 1];
    float w0 = bw[p0], w1 = bw[p1];
    float4 a = ((const float4*)(ybuf + (size_t)p0 * H_DIM))[h4];
    float4 b = ((const float4*)(ybuf + (size_t)p1 * H_DIM))[h4];
    float4 o;
    o.x = w0 * a.x + w1 * b.x;
    o.y = w0 * a.y + w1 * b.y;
    o.z = w0 * a.z + w1 * b.z;
    o.w = w0 * a.w + w1 * b.w;
    ((float4*)(out + (size_t)t * H_DIM))[h4] = o;
}

// =====================  PATH B: fallback (fp32 weights in-loop) ==============

__global__ __launch_bounds__(256, 2)
void gemm1_kernel(const unsigned short* __restrict__ Xb,
                  const float* __restrict__ W1,
                  const float* __restrict__ W3,
                  const int* __restrict__ counts,
                  const int* __restrict__ offsets,
                  const int* __restrict__ btok,
                  unsigned short* __restrict__ hbuf) {
    const int e = blockIdx.z;
    const int ne = counts[e];
    const int mt = blockIdx.y;
    if (mt * 128 >= ne) return;
    const int nt = blockIdx.x;
    const int off = offsets[e];

    __shared__ unsigned short sA[128][32];
    __shared__ unsigned short sB1[128][32];
    __shared__ unsigned short sB3[128][32];
    __shared__ int s_tok[128];

    const int tid = threadIdx.x;
    if (tid < 128) {
        int slot = mt * 128 + tid;
        s_tok[tid] = (slot < ne) ? btok[off + slot] : -1;
    }

    const float* __restrict__ pB1 = W1 + (size_t)e * I_DIM * H_DIM + (size_t)(nt * 128) * H_DIM;
    const float* __restrict__ pB3 = W3 + (size_t)e * I_DIM * H_DIM + (size_t)(nt * 128) * H_DIM;

    const int lane = tid & 63;
    const int wv = tid >> 6;
    const int wm = (wv >> 1) << 6;
    const int wn = (wv & 1) << 6;
    const int q = lane >> 4;
    const int c = lane & 15;

    f32x4 accg[4][4], accu[4][4];
    const f32x4 zero = {0.0f, 0.0f, 0.0f, 0.0f};
    #pragma unroll
    for (int i = 0; i < 4; ++i)
        #pragma unroll
        for (int j = 0; j < 4; ++j) { accg[i][j] = zero; accu[i][j] = zero; }

    const int srow = tid >> 2;
    const int schunk = (tid & 3) * 8;

    for (int kt = 0; kt < H_DIM; kt += 32) {
        __syncthreads();
        #pragma unroll
        for (int p = 0; p < 2; ++p) {
            int r = srow + p * 64;
            int tok = s_tok[r];
            u16x8 av = {0, 0, 0, 0, 0, 0, 0, 0};
            if (tok >= 0)
                av = *(const u16x8*)(Xb + (size_t)tok * H_DIM + kt + schunk);
            *(u16x8*)(&sA[r][schunk]) = av;

            const float* b1 = pB1 + (size_t)r * H_DIM + kt + schunk;
            *(u16x8*)(&sB1[r][schunk]) = cvt8(*(const float4*)(b1), *(const float4*)(b1 + 4));

            const float* b3 = pB3 + (size_t)r * H_DIM + kt + schunk;
            *(u16x8*)(&sB3[r][schunk]) = cvt8(*(const float4*)(b3), *(const float4*)(b3 + 4));
        }
        __syncthreads();

        bf16x8 af[4], b1f[4], b3f[4];
        #pragma unroll
        for (int i = 0; i < 4; ++i)
            af[i] = *(const bf16x8*)(&sA[wm + i * 16 + c][q * 8]);
        #pragma unroll
        for (int j = 0; j < 4; ++j) {
            b1f[j] = *(const bf16x8*)(&sB1[wn + j * 16 + c][q * 8]);
            b3f[j] = *(const bf16x8*)(&sB3[wn + j * 16 + c][q * 8]);
        }
        #pragma unroll
        for (int i = 0; i < 4; ++i)
            #pragma unroll
            for (int j = 0; j < 4; ++j) {
                accg[i][j] = __builtin_amdgcn_mfma_f32_16x16x32_bf16(af[i], b1f[j], accg[i][j], 0, 0, 0);
                accu[i][j] = __builtin_amdgcn_mfma_f32_16x16x32_bf16(af[i], b3f[j], accu[i][j], 0, 0, 0);
            }
    }

    #pragma unroll
    for (int i = 0; i < 4; ++i) {
        #pragma unroll
        for (int r = 0; r < 4; ++r) {
            int mloc = wm + i * 16 + q * 4 + r;
            int slot = mt * 128 + mloc;
            if (slot < ne) {
                size_t rowbase = (size_t)(off + slot) * I_DIM + nt * 128 + wn;
                #pragma unroll
                for (int j = 0; j < 4; ++j) {
                    float g = accg[i][j][r];
                    float u = accu[i][j][r];
                    float val = (g / (1.0f + __expf(-g))) * u;
                    hbuf[rowbase + j * 16 + c] = f2bf(val);
                }
            }
        }
    }
}

__global__ __launch_bounds__(256, 2)
void gemm2_kernel(const unsigned short* __restrict__ hbuf,
                  const float* __restrict__ W2,
                  const int* __restrict__ counts,
                  const int* __restrict__ offsets,
                  const int* __restrict__ btok,
                  const float* __restrict__ bw,
                  float* __restrict__ out) {
    const int e = blockIdx.z;
    const int ne = counts[e];
    const int mt = blockIdx.y;
    if (mt * 128 >= ne) return;
    const int nt = blockIdx.x;
    const int off = offsets[e];

    __shared__ unsigned short sA[128][32];
    __shared__ unsigned short sB[128][32];

    const int tid = threadIdx.x;
    const int lane = tid & 63;
    const int wv = tid >> 6;
    const int wm = (wv >> 1) << 6;
    const int wn = (wv & 1) << 6;
    const int q = lane >> 4;
    const int c = lane & 15;

    const float* __restrict__ pB = W2 + (size_t)e * H_DIM * I_DIM + (size_t)(nt * 128) * I_DIM;

    f32x4 acc[4][4];
    const f32x4 zero = {0.0f, 0.0f, 0.0f, 0.0f};
    #pragma unroll
    for (int i = 0; i < 4; ++i)
        #pragma unroll
        for (int j = 0; j < 4; ++j) acc[i][j] = zero;

    const int srow = tid >> 2;
    const int schunk = (tid & 3) * 8;

    for (int kt = 0; kt < I_DIM; kt += 32) {
        __syncthreads();
        #pragma unroll
        for (int p = 0; p < 2; ++p) {
            int r = srow + p * 64;
            int slot = mt * 128 + r;
            u16x8 av = {0, 0, 0, 0, 0, 0, 0, 0};
            if (slot < ne)
                av = *(const u16x8*)(hbuf + (size_t)(off + slot) * I_DIM + kt + schunk);
            *(u16x8*)(&sA[r][schunk]) = av;

            const float* b = pB + (size_t)r * I_DIM + kt + schunk;
            *(u16x8*)(&sB[r][schunk]) = cvt8(*(const float4*)(b), *(const float4*)(b + 4));
        }
        __syncthreads();

        bf16x8 af[4], bfr[4];
        #pragma unroll
        for (int i = 0; i < 4; ++i)
            af[i] = *(const bf16x8*)(&sA[wm + i * 16 + c][q * 8]);
        #pragma unroll
        for (int j = 0; j < 4; ++j)
            bfr[j] = *(const bf16x8*)(&sB[wn + j * 16 + c][q * 8]);
        #pragma unroll
        for (int i = 0; i < 4; ++i)
            #pragma unroll
            for (int j = 0; j < 4; ++j)
                acc[i][j] = __builtin_amdgcn_mfma_f32_16x16x32_bf16(af[i], bfr[j], acc[i][j], 0, 0, 0);
    }

    #pragma unroll
    for (int i = 0; i < 4; ++i) {
        #pragma unroll
        for (int r = 0; r < 4; ++r) {
            int mloc = wm + i * 16 + q * 4 + r;
            int slot = mt * 128 + mloc;
            if (slot < ne) {
                int tok = btok[off + slot];
                float wgt = bw[off + slot];
                float* obase = out + (size_t)tok * H_DIM + nt * 128 + wn;
                #pragma unroll
                for (int j = 0; j < 4; ++j)
                    atomicAdd(obase + j * 16 + c, wgt * acc[i][j][r]);
            }
        }
    }
}

// ============================================================================

extern "C" void kernel_launch(void* const* d_in, const int* in_sizes, int n_in,
                              void* d_out, int out_size, void* d_ws, size_t ws_size,
                              hipStream_t stream) {
    const float* hs = (const float*)d_in[0];   // [T, H]
    const float* rl = (const float*)d_in[1];   // [T, E]
    const float* w1 = (const float*)d_in[2];   // [E, I, H]
    const float* w3 = (const float*)d_in[3];   // [E, I, H]
    const float* w2 = (const float*)d_in[4];   // [E, H, I]
    float* out = (float*)d_out;

    char* ws = (char*)d_ws;
    // meta region (first 1 MB)
    int*   counts   = (int*)(ws);
    int*   offsets  = (int*)(ws + 256);
    int*   btok     = (int*)(ws + 4096);            // 8192 ints
    float* bw       = (float*)(ws + 36864);         // 8192 floats
    int*   tok2slot = (int*)(ws + 69632);           // 8192 ints

    const size_t MB = 1ull << 20;
    const size_t NEED_A = 146 * MB;

    if (ws_size >= NEED_A) {
        // -------- Path A: fused-convert pipelined GEMMs ---------------------
        unsigned short* Xb   = (unsigned short*)(ws + 1 * MB);     // 16 MB
        unsigned short* hbuf = (unsigned short*)(ws + 17 * MB);    // 64 MB
        float*          ybuf = (float*)(ws + 81 * MB);             // 64 MB

        routing_kernel<<<1, 256, 0, stream>>>(rl, counts, offsets, btok, bw, tok2slot);

        cvt_kernel<<<(T_TOK * H_DIM / 8) / 256, 256, 0, stream>>>(hs, Xb);

        gemm1p_kernel<<<dim3(I_DIM / 128, 32, N_EXP), 512, 0, stream>>>(
            Xb, w1, w3, counts, offsets, btok, hbuf);

        gemm2p_kernel<<<dim3(H_DIM / 256, 32, N_EXP), 512, 0, stream>>>(
            hbuf, w2, counts, offsets, ybuf);

        combine_kernel<<<(T_TOK * (H_DIM / 4)) / 256, 256, 0, stream>>>(
            ybuf, bw, tok2slot, out);
    } else {
        // -------- Path B: fallback (known-good round-1 structure) -----------
        unsigned short* Xb   = (unsigned short*)(ws + 1 * MB);            // 16 MB
        unsigned short* hbuf = (unsigned short*)(ws + 32 * MB);           // 64 MB

        hipMemsetAsync(out, 0, (size_t)T_TOK * H_DIM * sizeof(float), stream);

        routing_kernel<<<1, 256, 0, stream>>>(rl, counts, offsets, btok, bw, tok2slot);

        cvt_kernel<<<(T_TOK * H_DIM / 8) / 256, 256, 0, stream>>>(hs, Xb);

        gemm1_kernel<<<dim3(I_DIM / 128, T_TOK / 128, N_EXP), 256, 0, stream>>>(
            Xb, w1, w3, counts, offsets, btok, hbuf);

        gemm2_kernel<<<dim3(H_DIM / 128, T_TOK / 128, N_EXP), 256, 0, stream>>>(
            hbuf, w2, counts, offsets, btok, bw, out);
    }
}

// Round 6
// 1235.430 us; speedup vs baseline: 1.1858x; 1.0589x over previous
//
#include <hip/hip_runtime.h>
#include <stdint.h>

#define T_TOK 4096
#define H_DIM 2048
#define I_DIM 4096
#define N_EXP 8

typedef __attribute__((ext_vector_type(8))) short bf16x8;     // MFMA A/B frag (8 bf16)
typedef __attribute__((ext_vector_type(4))) float f32x4;      // MFMA C/D frag
typedef __attribute__((ext_vector_type(8))) unsigned short u16x8;

__device__ __forceinline__ unsigned short f2bf(float x) {
    union { float f; unsigned u; } v; v.f = x;
    unsigned r = v.u + 0x7FFF + ((v.u >> 16) & 1);   // RNE
    return (unsigned short)(r >> 16);
}

__device__ __forceinline__ u16x8 cvt8(float4 a, float4 b) {
    u16x8 o;
    o[0] = f2bf(a.x); o[1] = f2bf(a.y); o[2] = f2bf(a.z); o[3] = f2bf(a.w);
    o[4] = f2bf(b.x); o[5] = f2bf(b.y); o[6] = f2bf(b.z); o[7] = f2bf(b.w);
    return o;
}

// Direct global->LDS async copy, 16B per lane. LDS dest = wave-uniform base + lane*16.
__device__ __forceinline__ void async_cp16(const void* g, const unsigned short* lds_base) {
    __builtin_amdgcn_global_load_lds(
        (const __attribute__((address_space(1))) unsigned*)g,
        (__attribute__((address_space(3))) unsigned*)(unsigned)(uintptr_t)lds_base,
        16, 0, 0);
}

// ---------------- routing: top-2 + softmax + bucketize (single block) ----------
__global__ void routing_kernel(const float* __restrict__ logits,
                               int* __restrict__ counts, int* __restrict__ offsets,
                               int* __restrict__ btok, float* __restrict__ bw,
                               int* __restrict__ tok2slot) {
    __shared__ int s_cnt[N_EXP];
    __shared__ int s_off[N_EXP];
    __shared__ int s_cur[N_EXP];
    const int tid = threadIdx.x;   // 256 threads, 16 tokens each
    if (tid < N_EXP) s_cnt[tid] = 0;
    __syncthreads();

    int e0a[16], e1a[16]; float w0a[16], w1a[16];
    #pragma unroll
    for (int it = 0; it < 16; ++it) {
        int t = tid + it * 256;
        float l[8];
        #pragma unroll
        for (int e = 0; e < 8; ++e) l[e] = logits[t * 8 + e];
        int b0 = 0; float v0 = l[0];
        #pragma unroll
        for (int e = 1; e < 8; ++e) if (l[e] > v0) { v0 = l[e]; b0 = e; }
        int b1 = (b0 == 0) ? 1 : 0; float v1 = l[b1];
        #pragma unroll
        for (int e = 0; e < 8; ++e) if (e != b0 && l[e] > v1) { v1 = l[e]; b1 = e; }
        float w0 = 1.0f / (1.0f + __expf(v1 - v0));
        e0a[it] = b0; e1a[it] = b1; w0a[it] = w0; w1a[it] = 1.0f - w0;
        atomicAdd(&s_cnt[b0], 1);
        atomicAdd(&s_cnt[b1], 1);
    }
    __syncthreads();
    if (tid == 0) {
        int acc = 0;
        for (int e = 0; e < N_EXP; ++e) { s_off[e] = acc; s_cur[e] = acc; acc += s_cnt[e]; }
    }
    __syncthreads();
    if (tid < N_EXP) { counts[tid] = s_cnt[tid]; offsets[tid] = s_off[tid]; }
    #pragma unroll
    for (int it = 0; it < 16; ++it) {
        int t = tid + it * 256;
        int p0 = atomicAdd(&s_cur[e0a[it]], 1);
        btok[p0] = t; bw[p0] = w0a[it];
        int p1 = atomicAdd(&s_cur[e1a[it]], 1);
        btok[p1] = t; bw[p1] = w1a[it];
        tok2slot[2 * t] = p0;
        tok2slot[2 * t + 1] = p1;
    }
}

// ---------------- fp32 -> bf16 convert (8 floats / thread) -------------------
__global__ void cvt_kernel(const float* __restrict__ x, unsigned short* __restrict__ xb) {
    int i = blockIdx.x * blockDim.x + threadIdx.x;   // over groups of 8 floats
    float4 a = ((const float4*)x)[2 * i];
    float4 b = ((const float4*)x)[2 * i + 1];
    ((u16x8*)xb)[i] = cvt8(a, b);
}

// =====================  PATH A: fused-convert, multi-block/CU GEMMs ==========
//
// BM=128 x BN=128, 4 waves/block, ring-3 LDS so MULTIPLE independent blocks
// co-reside per CU (independent barrier groups hide each other's stalls —
// the 128KB 1-block/CU designs serialized the whole CU at every barrier).
//   phase h: {cvt+ds_write B(h+2) (regs loaded phase h-1) into slot (h+2)%3
//             | reload same regs with B(h+3) | 12 ds_read frags (slot h%3)
//             | 2 A gload_lds (h+2) | sched_barrier | setprio(1) MFMA
//             | setprio(0) | lgkmcnt(0) | vmcnt(10) | barrier}
// Invariants:
//   - ds_write at top of phase h targets slot (h+2)%3 == (h-1)%3, whose
//     readers (phase h-1) drained at the previous lgkmcnt(0)+barrier.
//   - vmcnt(10) at end of phase h: only this phase's 8 B-loads + 2 A-gloads
//     remain => A(h+1) (issued h-1) landed, B(h+2) regs (issued h-1)
//     retired via their cvt consumption. Tail: vmcnt(2) then vmcnt(0).
//   - B reg set consumed (cvt) one full phase after issue.
// Swizzle (verified conflict-free): LDS slot p of row r holds global chunk
// p ^ (((r&15)>>1)&3); A via pre-swizzled source + linear gload_lds dest,
// B via natural source chunk + swizzled ds_write; reads at q ^ ((c>>1)&3).

// GEMM1: h[slot,i] = silu(x@W1^T)*(x@W3^T). BM=128 x BN=128, 72KB, 2 blk/CU.
__global__ __launch_bounds__(256, 2)
void gemm1p_kernel(const unsigned short* __restrict__ Xb,
                   const float* __restrict__ W1,
                   const float* __restrict__ W3,
                   const int* __restrict__ counts,
                   const int* __restrict__ offsets,
                   const int* __restrict__ btok,
                   unsigned short* __restrict__ hbuf) {
    const int e = blockIdx.z;
    const int ne = counts[e];
    const int mt = blockIdx.y;
    if (mt * 128 >= ne) return;
    const int nt = blockIdx.x;
    const int off = offsets[e];

    __shared__ unsigned short sA[3][128 * 32];    // 24 KB
    __shared__ unsigned short sB1[3][128 * 32];   // 24 KB
    __shared__ unsigned short sB3[3][128 * 32];   // 24 KB -> 72 KB total

    const int tid = threadIdx.x;
    const int lane = tid & 63;
    const int wv = tid >> 6;         // 0..3
    const int wm = (wv >> 1) << 6;   // {0,64}
    const int wn = (wv & 1) << 6;    // {0,64}
    const int q = lane >> 4;
    const int c = lane & 15;
    const int xq = q ^ ((c >> 1) & 3);          // swizzled read slot

    const int aoff = (wm + c) * 32 + xq * 8;
    const int boff = (wn + c) * 32 + xq * 8;

    // A staging: per wave 16 rows per gload; rows arow and arow+64
    const int arow = wv * 16 + (lane >> 2);           // 0..63
    const int sgA = (lane & 3) ^ ((lane >> 3) & 3);

    int sl0 = mt * 128 + arow;       if (sl0 >= ne) sl0 = ne - 1;
    int sl1 = mt * 128 + arow + 64;  if (sl1 >= ne) sl1 = ne - 1;
    const unsigned short* gA0 = Xb + (size_t)btok[off + sl0] * H_DIM + sgA * 8;
    const unsigned short* gA1 = Xb + (size_t)btok[off + sl1] * H_DIM + sgA * 8;
    const int dofsA0 = wv * 512;
    const int dofsA1 = 2048 + wv * 512;

    // B staging: thread -> rows brow, brow+64; natural chunk (tid&3), swizzled write
    const int brow = tid >> 2;                        // 0..63
    const int sgB = (tid & 3) ^ ((tid >> 3) & 3);
    const size_t wrow = (size_t)e * I_DIM + nt * 128 + brow;
    const float* gW1  = W1 + wrow * H_DIM + (tid & 3) * 8;
    const float* gW1b = gW1 + (size_t)64 * H_DIM;
    const float* gW3  = W3 + wrow * H_DIM + (tid & 3) * 8;
    const float* gW3b = gW3 + (size_t)64 * H_DIM;
    const int bwro  = brow * 32 + sgB * 8;
    const int bwro2 = bwro + 2048;

    f32x4 accg[4][4], accu[4][4];
    const f32x4 zero = {0.0f, 0.0f, 0.0f, 0.0f};
    #pragma unroll
    for (int i = 0; i < 4; ++i)
        #pragma unroll
        for (int j = 0; j < 4; ++j) { accg[i][j] = zero; accu[i][j] = zero; }

    float4 w0, w1, w2, w3, w4, w5, w6, w7;

    // ---- prologue: B halves 0,1 direct; A gloads 0,1; prime B(2) regs ----
    #pragma unroll
    for (int h = 0; h < 2; ++h) {
        const float* p1  = gW1  + h * 32;
        const float* p1b = gW1b + h * 32;
        const float* p3  = gW3  + h * 32;
        const float* p3b = gW3b + h * 32;
        *(u16x8*)(&sB1[h][bwro])  = cvt8(((const float4*)p1)[0],  ((const float4*)p1)[1]);
        *(u16x8*)(&sB1[h][bwro2]) = cvt8(((const float4*)p1b)[0], ((const float4*)p1b)[1]);
        *(u16x8*)(&sB3[h][bwro])  = cvt8(((const float4*)p3)[0],  ((const float4*)p3)[1]);
        *(u16x8*)(&sB3[h][bwro2]) = cvt8(((const float4*)p3b)[0], ((const float4*)p3b)[1]);
    }
    async_cp16(gA0,      &sA[0][dofsA0]);
    async_cp16(gA1,      &sA[0][dofsA1]);
    async_cp16(gA0 + 32, &sA[1][dofsA0]);
    async_cp16(gA1 + 32, &sA[1][dofsA1]);
    // B(2) -> regs (consumed at phase 0's write of slot 2)
    w0 = ((const float4*)(gW1  + 64))[0]; w1 = ((const float4*)(gW1  + 64))[1];
    w2 = ((const float4*)(gW1b + 64))[0]; w3 = ((const float4*)(gW1b + 64))[1];
    w4 = ((const float4*)(gW3  + 64))[0]; w5 = ((const float4*)(gW3  + 64))[1];
    w6 = ((const float4*)(gW3b + 64))[0]; w7 = ((const float4*)(gW3b + 64))[1];

    asm volatile("s_waitcnt lgkmcnt(0)" ::: "memory");
    asm volatile("s_waitcnt vmcnt(10)" ::: "memory");   // half 0's A landed
    __builtin_amdgcn_s_barrier();
    __builtin_amdgcn_sched_barrier(0);

    const int NT = H_DIM / 32;   // 64

#define G1_PH(H, S, S2)                                                                              \
    {                                                                                                \
        if ((H) + 2 < NT) {                                                                          \
            *(u16x8*)(&sB1[S2][bwro])  = cvt8(w0, w1);                                               \
            *(u16x8*)(&sB1[S2][bwro2]) = cvt8(w2, w3);                                               \
            *(u16x8*)(&sB3[S2][bwro])  = cvt8(w4, w5);                                               \
            *(u16x8*)(&sB3[S2][bwro2]) = cvt8(w6, w7);                                               \
        }                                                                                            \
        if ((H) + 3 < NT) {                                                                          \
            const float* p1  = gW1  + (size_t)((H) + 3) * 32;                                        \
            const float* p1b = gW1b + (size_t)((H) + 3) * 32;                                        \
            const float* p3  = gW3  + (size_t)((H) + 3) * 32;                                        \
            const float* p3b = gW3b + (size_t)((H) + 3) * 32;                                        \
            w0 = ((const float4*)p1)[0];  w1 = ((const float4*)p1)[1];                               \
            w2 = ((const float4*)p1b)[0]; w3 = ((const float4*)p1b)[1];                              \
            w4 = ((const float4*)p3)[0];  w5 = ((const float4*)p3)[1];                               \
            w6 = ((const float4*)p3b)[0]; w7 = ((const float4*)p3b)[1];                              \
        }                                                                                            \
        bf16x8 af[4], b1f[4], b3f[4];                                                                \
        _Pragma("unroll")                                                                            \
        for (int i = 0; i < 4; ++i) af[i]  = *(const bf16x8*)(&sA[S][aoff + i * 512]);               \
        _Pragma("unroll")                                                                            \
        for (int j = 0; j < 4; ++j) b1f[j] = *(const bf16x8*)(&sB1[S][boff + j * 512]);              \
        _Pragma("unroll")                                                                            \
        for (int j = 0; j < 4; ++j) b3f[j] = *(const bf16x8*)(&sB3[S][boff + j * 512]);              \
        if ((H) + 2 < NT) {                                                                          \
            async_cp16(gA0 + ((H) + 2) * 32, &sA[S2][dofsA0]);                                       \
            async_cp16(gA1 + ((H) + 2) * 32, &sA[S2][dofsA1]);                                       \
        }                                                                                            \
        __builtin_amdgcn_sched_barrier(0);                                                           \
        __builtin_amdgcn_s_setprio(1);                                                               \
        _Pragma("unroll")                                                                            \
        for (int i = 0; i < 4; ++i)                                                                  \
            _Pragma("unroll")                                                                        \
            for (int j = 0; j < 4; ++j)                                                              \
                accg[i][j] = __builtin_amdgcn_mfma_f32_16x16x32_bf16(af[i], b1f[j], accg[i][j], 0, 0, 0); \
        _Pragma("unroll")                                                                            \
        for (int i = 0; i < 4; ++i)                                                                  \
            _Pragma("unroll")                                                                        \
            for (int j = 0; j < 4; ++j)                                                              \
                accu[i][j] = __builtin_amdgcn_mfma_f32_16x16x32_bf16(af[i], b3f[j], accu[i][j], 0, 0, 0); \
        __builtin_amdgcn_s_setprio(0);                                                               \
        if ((H) + 1 < NT) {                                                                          \
            asm volatile("s_waitcnt lgkmcnt(0)" ::: "memory");                                       \
            if ((H) + 3 < NT)      asm volatile("s_waitcnt vmcnt(10)" ::: "memory");                 \
            else if ((H) + 2 < NT) asm volatile("s_waitcnt vmcnt(2)" ::: "memory");                  \
            else                   asm volatile("s_waitcnt vmcnt(0)" ::: "memory");                  \
            __builtin_amdgcn_s_barrier();                                                            \
            __builtin_amdgcn_sched_barrier(0);                                                       \
        }                                                                                            \
    }

    int h = 0;
    for (int t = 0; t < 21; ++t) {       // covers h = 0..62
        G1_PH(h,     0, 2);
        G1_PH(h + 1, 1, 0);
        G1_PH(h + 2, 2, 1);
        h += 3;
    }
    G1_PH(63, 0, 2);                      // 63 % 3 == 0
#undef G1_PH

    // epilogue: silu(gate)*up -> bf16
    #pragma unroll
    for (int i = 0; i < 4; ++i) {
        #pragma unroll
        for (int r = 0; r < 4; ++r) {
            int mloc = wm + i * 16 + q * 4 + r;
            int slot = mt * 128 + mloc;
            if (slot < ne) {
                size_t rowbase = (size_t)(off + slot) * I_DIM + nt * 128 + wn;
                #pragma unroll
                for (int j = 0; j < 4; ++j) {
                    float g = accg[i][j][r];
                    float u = accu[i][j][r];
                    float val = (g / (1.0f + __expf(-g))) * u;
                    hbuf[rowbase + j * 16 + c] = f2bf(val);
                }
            }
        }
    }
}

// GEMM2: y[slot,h] = h[slot] @ W2^T. BM=128 x BN=128, 48KB, 3 blk/CU.
__global__ __launch_bounds__(256, 3)
void gemm2p_kernel(const unsigned short* __restrict__ hbuf,
                   const float* __restrict__ W2,
                   const int* __restrict__ counts,
                   const int* __restrict__ offsets,
                   float* __restrict__ ybuf) {
    const int e = blockIdx.z;
    const int ne = counts[e];
    const int mt = blockIdx.y;
    if (mt * 128 >= ne) return;
    const int nt = blockIdx.x;
    const int off = offsets[e];

    __shared__ unsigned short sA[3][128 * 32];   // 24 KB
    __shared__ unsigned short sB[3][128 * 32];   // 24 KB -> 48 KB total

    const int tid = threadIdx.x;
    const int lane = tid & 63;
    const int wv = tid >> 6;
    const int wm = (wv >> 1) << 6;
    const int wn = (wv & 1) << 6;
    const int q = lane >> 4;
    const int c = lane & 15;
    const int xq = q ^ ((c >> 1) & 3);

    const int aoff = (wm + c) * 32 + xq * 8;
    const int boff = (wn + c) * 32 + xq * 8;

    const int arow = wv * 16 + (lane >> 2);
    const int sgA = (lane & 3) ^ ((lane >> 3) & 3);
    int sl0 = mt * 128 + arow;       if (sl0 >= ne) sl0 = ne - 1;
    int sl1 = mt * 128 + arow + 64;  if (sl1 >= ne) sl1 = ne - 1;
    const unsigned short* gA0 = hbuf + (size_t)(off + sl0) * I_DIM + sgA * 8;
    const unsigned short* gA1 = hbuf + (size_t)(off + sl1) * I_DIM + sgA * 8;
    const int dofsA0 = wv * 512;
    const int dofsA1 = 2048 + wv * 512;

    const int brow = tid >> 2;
    const int sgB = (tid & 3) ^ ((tid >> 3) & 3);
    const size_t wrow = (size_t)e * H_DIM + nt * 128 + brow;
    const float* gB  = W2 + wrow * I_DIM + (tid & 3) * 8;
    const float* gBb = gB + (size_t)64 * I_DIM;
    const int bwro  = brow * 32 + sgB * 8;
    const int bwro2 = bwro + 2048;

    f32x4 acc[4][4];
    const f32x4 zero = {0.0f, 0.0f, 0.0f, 0.0f};
    #pragma unroll
    for (int i = 0; i < 4; ++i)
        #pragma unroll
        for (int j = 0; j < 4; ++j) acc[i][j] = zero;

    float4 w0, w1, w2, w3;

    // ---- prologue ----
    #pragma unroll
    for (int h = 0; h < 2; ++h) {
        const float* p  = gB  + h * 32;
        const float* pb = gBb + h * 32;
        *(u16x8*)(&sB[h][bwro])  = cvt8(((const float4*)p)[0],  ((const float4*)p)[1]);
        *(u16x8*)(&sB[h][bwro2]) = cvt8(((const float4*)pb)[0], ((const float4*)pb)[1]);
    }
    async_cp16(gA0,      &sA[0][dofsA0]);
    async_cp16(gA1,      &sA[0][dofsA1]);
    async_cp16(gA0 + 32, &sA[1][dofsA0]);
    async_cp16(gA1 + 32, &sA[1][dofsA1]);
    w0 = ((const float4*)(gB  + 64))[0]; w1 = ((const float4*)(gB  + 64))[1];
    w2 = ((const float4*)(gBb + 64))[0]; w3 = ((const float4*)(gBb + 64))[1];

    asm volatile("s_waitcnt lgkmcnt(0)" ::: "memory");
    asm volatile("s_waitcnt vmcnt(6)" ::: "memory");
    __builtin_amdgcn_s_barrier();
    __builtin_amdgcn_sched_barrier(0);

    const int NT = I_DIM / 32;   // 128

#define G2_PH(H, S, S2)                                                                              \
    {                                                                                                \
        if ((H) + 2 < NT) {                                                                          \
            *(u16x8*)(&sB[S2][bwro])  = cvt8(w0, w1);                                                \
            *(u16x8*)(&sB[S2][bwro2]) = cvt8(w2, w3);                                                \
        }                                                                                            \
        if ((H) + 3 < NT) {                                                                          \
            const float* p  = gB  + (size_t)((H) + 3) * 32;                                          \
            const float* pb = gBb + (size_t)((H) + 3) * 32;                                          \
            w0 = ((const float4*)p)[0];  w1 = ((const float4*)p)[1];                                 \
            w2 = ((const float4*)pb)[0]; w3 = ((const float4*)pb)[1];                                \
        }                                                                                            \
        bf16x8 af[4], bfr[4];                                                                        \
        _Pragma("unroll")                                                                            \
        for (int i = 0; i < 4; ++i) af[i]  = *(const bf16x8*)(&sA[S][aoff + i * 512]);               \
        _Pragma("unroll")                                                                            \
        for (int j = 0; j < 4; ++j) bfr[j] = *(const bf16x8*)(&sB[S][boff + j * 512]);               \
        if ((H) + 2 < NT) {                                                                          \
            async_cp16(gA0 + ((H) + 2) * 32, &sA[S2][dofsA0]);                                       \
            async_cp16(gA1 + ((H) + 2) * 32, &sA[S2][dofsA1]);                                       \
        }                                                                                            \
        __builtin_amdgcn_sched_barrier(0);                                                           \
        __builtin_amdgcn_s_setprio(1);                                                               \
        _Pragma("unroll")                                                                            \
        for (int i = 0; i < 4; ++i)                                                                  \
            _Pragma("unroll")                                                                        \
            for (int j = 0; j < 4; ++j)                                                              \
                acc[i][j] = __builtin_amdgcn_mfma_f32_16x16x32_bf16(af[i], bfr[j], acc[i][j], 0, 0, 0); \
        __builtin_amdgcn_s_setprio(0);                                                               \
        if ((H) + 1 < NT) {                                                                          \
            asm volatile("s_waitcnt lgkmcnt(0)" ::: "memory");                                       \
            if ((H) + 3 < NT)      asm volatile("s_waitcnt vmcnt(6)" ::: "memory");                  \
            else if ((H) + 2 < NT) asm volatile("s_waitcnt vmcnt(2)" ::: "memory");                  \
            else                   asm volatile("s_waitcnt vmcnt(0)" ::: "memory");                  \
            __builtin_amdgcn_s_barrier();                                                            \
            __builtin_amdgcn_sched_barrier(0);                                                       \
        }                                                                                            \
    }

    int h = 0;
    for (int t = 0; t < 42; ++t) {       // covers h = 0..125
        G2_PH(h,     0, 2);
        G2_PH(h + 1, 1, 0);
        G2_PH(h + 2, 2, 1);
        h += 3;
    }
    G2_PH(126, 0, 2);                     // 126 % 3 == 0
    G2_PH(127, 1, 0);                     // 127 % 3 == 1
#undef G2_PH

    #pragma unroll
    for (int i = 0; i < 4; ++i) {
        #pragma unroll
        for (int r = 0; r < 4; ++r) {
            int mloc = wm + i * 16 + q * 4 + r;
            int slot = mt * 128 + mloc;
            if (slot < ne) {
                float* obase = ybuf + (size_t)(off + slot) * H_DIM + nt * 128 + wn;
                #pragma unroll
                for (int j = 0; j < 4; ++j)
                    obase[j * 16 + c] = acc[i][j][r];
            }
        }
    }
}

// combine: out[t] = w0 * y[slot0] + w1 * y[slot1]
__global__ void combine_kernel(const float* __restrict__ ybuf,
                               const float* __restrict__ bw,
                               const int* __restrict__ tok2slot,
                               float* __restrict__ out) {
    int i = blockIdx.x * blockDim.x + threadIdx.x;   // over float4 of out
    int t = i >> 9;            // H/4 = 512
    int h4 = i & 511;
    int p0 = tok2slot[2 * t], p1 = tok2slot[2 * t + 1];
    float w0 = bw[p0], w1 = bw[p1];
    float4 a = ((const float4*)(ybuf + (size_t)p0 * H_DIM))[h4];
    float4 b = ((const float4*)(ybuf + (size_t)p1 * H_DIM))[h4];
    float4 o;
    o.x = w0 * a.x + w1 * b.x;
    o.y = w0 * a.y + w1 * b.y;
    o.z = w0 * a.z + w1 * b.z;
    o.w = w0 * a.w + w1 * b.w;
    ((float4*)(out + (size_t)t * H_DIM))[h4] = o;
}

// =====================  PATH B: fallback (fp32 weights in-loop) ==============

__global__ __launch_bounds__(256, 2)
void gemm1_kernel(const unsigned short* __restrict__ Xb,
                  const float* __restrict__ W1,
                  const float* __restrict__ W3,
                  const int* __restrict__ counts,
                  const int* __restrict__ offsets,
                  const int* __restrict__ btok,
                  unsigned short* __restrict__ hbuf) {
    const int e = blockIdx.z;
    const int ne = counts[e];
    const int mt = blockIdx.y;
    if (mt * 128 >= ne) return;
    const int nt = blockIdx.x;
    const int off = offsets[e];

    __shared__ unsigned short sA[128][32];
    __shared__ unsigned short sB1[128][32];
    __shared__ unsigned short sB3[128][32];
    __shared__ int s_tok[128];

    const int tid = threadIdx.x;
    if (tid < 128) {
        int slot = mt * 128 + tid;
        s_tok[tid] = (slot < ne) ? btok[off + slot] : -1;
    }

    const float* __restrict__ pB1 = W1 + (size_t)e * I_DIM * H_DIM + (size_t)(nt * 128) * H_DIM;
    const float* __restrict__ pB3 = W3 + (size_t)e * I_DIM * H_DIM + (size_t)(nt * 128) * H_DIM;

    const int lane = tid & 63;
    const int wv = tid >> 6;
    const int wm = (wv >> 1) << 6;
    const int wn = (wv & 1) << 6;
    const int q = lane >> 4;
    const int c = lane & 15;

    f32x4 accg[4][4], accu[4][4];
    const f32x4 zero = {0.0f, 0.0f, 0.0f, 0.0f};
    #pragma unroll
    for (int i = 0; i < 4; ++i)
        #pragma unroll
        for (int j = 0; j < 4; ++j) { accg[i][j] = zero; accu[i][j] = zero; }

    const int srow = tid >> 2;
    const int schunk = (tid & 3) * 8;

    for (int kt = 0; kt < H_DIM; kt += 32) {
        __syncthreads();
        #pragma unroll
        for (int p = 0; p < 2; ++p) {
            int r = srow + p * 64;
            int tok = s_tok[r];
            u16x8 av = {0, 0, 0, 0, 0, 0, 0, 0};
            if (tok >= 0)
                av = *(const u16x8*)(Xb + (size_t)tok * H_DIM + kt + schunk);
            *(u16x8*)(&sA[r][schunk]) = av;

            const float* b1 = pB1 + (size_t)r * H_DIM + kt + schunk;
            *(u16x8*)(&sB1[r][schunk]) = cvt8(*(const float4*)(b1), *(const float4*)(b1 + 4));

            const float* b3 = pB3 + (size_t)r * H_DIM + kt + schunk;
            *(u16x8*)(&sB3[r][schunk]) = cvt8(*(const float4*)(b3), *(const float4*)(b3 + 4));
        }
        __syncthreads();

        bf16x8 af[4], b1f[4], b3f[4];
        #pragma unroll
        for (int i = 0; i < 4; ++i)
            af[i] = *(const bf16x8*)(&sA[wm + i * 16 + c][q * 8]);
        #pragma unroll
        for (int j = 0; j < 4; ++j) {
            b1f[j] = *(const bf16x8*)(&sB1[wn + j * 16 + c][q * 8]);
            b3f[j] = *(const bf16x8*)(&sB3[wn + j * 16 + c][q * 8]);
        }
        #pragma unroll
        for (int i = 0; i < 4; ++i)
            #pragma unroll
            for (int j = 0; j < 4; ++j) {
                accg[i][j] = __builtin_amdgcn_mfma_f32_16x16x32_bf16(af[i], b1f[j], accg[i][j], 0, 0, 0);
                accu[i][j] = __builtin_amdgcn_mfma_f32_16x16x32_bf16(af[i], b3f[j], accu[i][j], 0, 0, 0);
            }
    }

    #pragma unroll
    for (int i = 0; i < 4; ++i) {
        #pragma unroll
        for (int r = 0; r < 4; ++r) {
            int mloc = wm + i * 16 + q * 4 + r;
            int slot = mt * 128 + mloc;
            if (slot < ne) {
                size_t rowbase = (size_t)(off + slot) * I_DIM + nt * 128 + wn;
                #pragma unroll
                for (int j = 0; j < 4; ++j) {
                    float g = accg[i][j][r];
                    float u = accu[i][j][r];
                    float val = (g / (1.0f + __expf(-g))) * u;
                    hbuf[rowbase + j * 16 + c] = f2bf(val);
                }
            }
        }
    }
}

__global__ __launch_bounds__(256, 2)
void gemm2_kernel(const unsigned short* __restrict__ hbuf,
                  const float* __restrict__ W2,
                  const int* __restrict__ counts,
                  const int* __restrict__ offsets,
                  const int* __restrict__ btok,
                  const float* __restrict__ bw,
                  float* __restrict__ out) {
    const int e = blockIdx.z;
    const int ne = counts[e];
    const int mt = blockIdx.y;
    if (mt * 128 >= ne) return;
    const int nt = blockIdx.x;
    const int off = offsets[e];

    __shared__ unsigned short sA[128][32];
    __shared__ unsigned short sB[128][32];

    const int tid = threadIdx.x;
    const int lane = tid & 63;
    const int wv = tid >> 6;
    const int wm = (wv >> 1) << 6;
    const int wn = (wv & 1) << 6;
    const int q = lane >> 4;
    const int c = lane & 15;

    const float* __restrict__ pB = W2 + (size_t)e * H_DIM * I_DIM + (size_t)(nt * 128) * I_DIM;

    f32x4 acc[4][4];
    const f32x4 zero = {0.0f, 0.0f, 0.0f, 0.0f};
    #pragma unroll
    for (int i = 0; i < 4; ++i)
        #pragma unroll
        for (int j = 0; j < 4; ++j) acc[i][j] = zero;

    const int srow = tid >> 2;
    const int schunk = (tid & 3) * 8;

    for (int kt = 0; kt < I_DIM; kt += 32) {
        __syncthreads();
        #pragma unroll
        for (int p = 0; p < 2; ++p) {
            int r = srow + p * 64;
            int slot = mt * 128 + r;
            u16x8 av = {0, 0, 0, 0, 0, 0, 0, 0};
            if (slot < ne)
                av = *(const u16x8*)(hbuf + (size_t)(off + slot) * I_DIM + kt + schunk);
            *(u16x8*)(&sA[r][schunk]) = av;

            const float* b = pB + (size_t)r * I_DIM + kt + schunk;
            *(u16x8*)(&sB[r][schunk]) = cvt8(*(const float4*)(b), *(const float4*)(b + 4));
        }
        __syncthreads();

        bf16x8 af[4], bfr[4];
        #pragma unroll
        for (int i = 0; i < 4; ++i)
            af[i] = *(const bf16x8*)(&sA[wm + i * 16 + c][q * 8]);
        #pragma unroll
        for (int j = 0; j < 4; ++j)
            bfr[j] = *(const bf16x8*)(&sB[wn + j * 16 + c][q * 8]);
        #pragma unroll
        for (int i = 0; i < 4; ++i)
            #pragma unroll
            for (int j = 0; j < 4; ++j)
                acc[i][j] = __builtin_amdgcn_mfma_f32_16x16x32_bf16(af[i], bfr[j], acc[i][j], 0, 0, 0);
    }

    #pragma unroll
    for (int i = 0; i < 4; ++i) {
        #pragma unroll
        for (int r = 0; r < 4; ++r) {
            int mloc = wm + i * 16 + q * 4 + r;
            int slot = mt * 128 + mloc;
            if (slot < ne) {
                int tok = btok[off + slot];
                float wgt = bw[off + slot];
                float* obase = out + (size_t)tok * H_DIM + nt * 128 + wn;
                #pragma unroll
                for (int j = 0; j < 4; ++j)
                    atomicAdd(obase + j * 16 + c, wgt * acc[i][j][r]);
            }
        }
    }
}

// ============================================================================

extern "C" void kernel_launch(void* const* d_in, const int* in_sizes, int n_in,
                              void* d_out, int out_size, void* d_ws, size_t ws_size,
                              hipStream_t stream) {
    const float* hs = (const float*)d_in[0];   // [T, H]
    const float* rl = (const float*)d_in[1];   // [T, E]
    const float* w1 = (const float*)d_in[2];   // [E, I, H]
    const float* w3 = (const float*)d_in[3];   // [E, I, H]
    const float* w2 = (const float*)d_in[4];   // [E, H, I]
    float* out = (float*)d_out;

    char* ws = (char*)d_ws;
    // meta region (first 1 MB)
    int*   counts   = (int*)(ws);
    int*   offsets  = (int*)(ws + 256);
    int*   btok     = (int*)(ws + 4096);            // 8192 ints
    float* bw       = (float*)(ws + 36864);         // 8192 floats
    int*   tok2slot = (int*)(ws + 69632);           // 8192 ints

    const size_t MB = 1ull << 20;
    const size_t NEED_A = 146 * MB;

    if (ws_size >= NEED_A) {
        // -------- Path A: fused-convert, multi-block/CU GEMMs ---------------
        unsigned short* Xb   = (unsigned short*)(ws + 1 * MB);     // 16 MB
        unsigned short* hbuf = (unsigned short*)(ws + 17 * MB);    // 64 MB
        float*          ybuf = (float*)(ws + 81 * MB);             // 64 MB

        routing_kernel<<<1, 256, 0, stream>>>(rl, counts, offsets, btok, bw, tok2slot);

        cvt_kernel<<<(T_TOK * H_DIM / 8) / 256, 256, 0, stream>>>(hs, Xb);

        gemm1p_kernel<<<dim3(I_DIM / 128, 64, N_EXP), 256, 0, stream>>>(
            Xb, w1, w3, counts, offsets, btok, hbuf);

        gemm2p_kernel<<<dim3(H_DIM / 128, 64, N_EXP), 256, 0, stream>>>(
            hbuf, w2, counts, offsets, ybuf);

        combine_kernel<<<(T_TOK * (H_DIM / 4)) / 256, 256, 0, stream>>>(
            ybuf, bw, tok2slot, out);
    } else {
        // -------- Path B: fallback (known-good round-1 structure) -----------
        unsigned short* Xb   = (unsigned short*)(ws + 1 * MB);            // 16 MB
        unsigned short* hbuf = (unsigned short*)(ws + 32 * MB);           // 64 MB

        hipMemsetAsync(out, 0, (size_t)T_TOK * H_DIM * sizeof(float), stream);

        routing_kernel<<<1, 256, 0, stream>>>(rl, counts, offsets, btok, bw, tok2slot);

        cvt_kernel<<<(T_TOK * H_DIM / 8) / 256, 256, 0, stream>>>(hs, Xb);

        gemm1_kernel<<<dim3(I_DIM / 128, T_TOK / 128, N_EXP), 256, 0, stream>>>(
            Xb, w1, w3, counts, offsets, btok, hbuf);

        gemm2_kernel<<<dim3(H_DIM / 128, T_TOK / 128, N_EXP), 256, 0, stream>>>(
            hbuf, w2, counts, offsets, btok, bw, out);
    }
}